// Round 1
// baseline (6590.919 us; speedup 1.0000x reference)
//
#include <hip/hip_runtime.h>
#include <hip/hip_bf16.h>

constexpr int B_ = 8;
constexpr int N_ = 1024;      // nodes
constexpr int C_ = 128;       // channels
constexpr int EL_ = 196;      // local edges
constexpr int ET_ = N_ + EL_; // 1220 total edges
constexpr int KNN_ = 11;      // k+1
constexpr int CAP_ = 256;     // per-node edge-list capacity

// ---------------- x2 = sum(x*x) per row ----------------
__global__ void k_x2(const float* __restrict__ X, float* __restrict__ x2) {
    int row = blockIdx.x * 4 + (threadIdx.x >> 6);
    int lane = threadIdx.x & 63;
    const float* xr = X + (size_t)row * C_;
    float a = xr[lane], b = xr[lane + 64];
    float s = a * a + b * b;
    #pragma unroll
    for (int off = 32; off > 0; off >>= 1) s += __shfl_down(s, off, 64);
    if (lane == 0) x2[row] = s;
}

__device__ __forceinline__ bool lessKI(float da, int ia, float db, int ib) {
    return (da < db) || (da == db && ia < ib);
}

// ---------------- distances + stable argsort per row ----------------
__global__ __launch_bounds__(256) void k_distsort(const float* __restrict__ X,
                                                  const float* __restrict__ x2,
                                                  int* __restrict__ order) {
    __shared__ float sd[N_];
    __shared__ int si[N_];
    __shared__ __align__(16) float xn[C_];
    int rn = blockIdx.x;           // 0..B*N-1
    int b = rn >> 10, n = rn & 1023;
    int tid = threadIdx.x;
    if (tid < C_) xn[tid] = X[((size_t)(b * N_ + n)) * C_ + tid];
    __syncthreads();
    float x2n = x2[b * N_ + n];
    const float4* xn4 = (const float4*)xn;
    #pragma unroll
    for (int q = 0; q < 4; ++q) {
        int m = tid + q * 256;
        const float4* xm4 = (const float4*)(X + ((size_t)(b * N_ + m)) * C_);
        float dot = 0.f;
        #pragma unroll
        for (int k = 0; k < 32; ++k) {
            float4 a = xm4[k], c = xn4[k];
            dot += a.x * c.x + a.y * c.y + a.z * c.z + a.w * c.w;
        }
        sd[m] = x2n - 2.f * dot + x2[b * N_ + m];
        si[m] = m;
    }
    // bitonic sort ascending by (dist, idx)  == stable argsort
    for (int ksz = 2; ksz <= N_; ksz <<= 1) {
        for (int j = ksz >> 1; j > 0; j >>= 1) {
            __syncthreads();
            for (int l = tid; l < N_; l += 256) {
                int p = l ^ j;
                if (p > l) {
                    float dl = sd[l], dp = sd[p];
                    int il = si[l], ip = si[p];
                    bool asc = ((l & ksz) == 0);
                    bool dosw = asc ? lessKI(dp, ip, dl, il) : lessKI(dl, il, dp, ip);
                    if (dosw) { sd[l] = dp; sd[p] = dl; si[l] = ip; si[p] = il; }
                }
            }
        }
    }
    __syncthreads();
    for (int l = tid; l < N_; l += 256)
        order[(size_t)rn * N_ + l] = si[l];
}

// ---------------- H1 node degrees (top-11) ----------------
__global__ void k_h1deg(const int* __restrict__ order, int* __restrict__ Dv) {
    int rn = blockIdx.x * blockDim.x + threadIdx.x;
    if (rn >= B_ * N_) return;
    int b = rn >> 10;
    const int* o = order + (size_t)rn * N_;
    for (int t = 0; t < KNN_; ++t) atomicAdd(&Dv[b * N_ + o[t]], 1);
}

// ---------------- local edge member lists (same for all b) ----------------
__global__ void k_locbuild(const float* __restrict__ localH, int* __restrict__ locCnt,
                           int* __restrict__ locList) {
    int le = blockIdx.x * blockDim.x + threadIdx.x;
    if (le >= EL_) return;
    int c = 0;
    for (int n = 0; n < N_; ++n)
        if (localH[(size_t)n * EL_ + le] != 0.0f) locList[le * 32 + (c++)] = n;
    locCnt[le] = c;
}

// ---------------- per-edge: fill node->edge lists, recipDE ----------------
__global__ void k_edgefill(const int* __restrict__ order, const int* __restrict__ Dv,
                           const int* __restrict__ locCnt, const int* __restrict__ locList,
                           int* __restrict__ nodeCnt, int* __restrict__ nodeList,
                           float* __restrict__ recipDE) {
    int idx = blockIdx.x * blockDim.x + threadIdx.x;
    if (idx >= B_ * ET_) return;
    int b = idx / ET_, e = idx % ET_;
    int cnt;
    if (e < N_) {
        cnt = Dv[b * N_ + e];
        const int* o = order + ((size_t)(b * N_ + e)) * N_;
        for (int t = 0; t < cnt; ++t) {
            int j = o[t];
            int pos = atomicAdd(&nodeCnt[b * N_ + j], 1);
            if (pos < CAP_) nodeList[((size_t)(b * N_ + j)) * CAP_ + pos] = e;
        }
    } else {
        int le = e - N_;
        cnt = locCnt[le];
        for (int t = 0; t < cnt; ++t) {
            int j = locList[le * 32 + t];
            int pos = atomicAdd(&nodeCnt[b * N_ + j], 1);
            if (pos < CAP_) nodeList[((size_t)(b * N_ + j)) * CAP_ + pos] = e;
        }
    }
    recipDE[idx] = 1.0f / (float)cnt;
}

// ---------------- sort node lists (determinism) + recipDV ----------------
__global__ void k_sortlists(int* __restrict__ nodeCnt, int* __restrict__ nodeList,
                            float* __restrict__ recipDV) {
    int rn = blockIdx.x * blockDim.x + threadIdx.x;
    if (rn >= B_ * N_) return;
    int cnt = nodeCnt[rn];
    if (cnt > CAP_) cnt = CAP_;
    int* lst = nodeList + (size_t)rn * CAP_;
    for (int i = 1; i < cnt; ++i) {
        int v = lst[i];
        int j = i - 1;
        while (j >= 0 && lst[j] > v) { lst[j + 1] = lst[j]; --j; }
        lst[j + 1] = v;
    }
    recipDV[rn] = 1.0f / (float)cnt;
    nodeCnt[rn] = cnt;
}

// ---------------- edge gather helper ----------------
__device__ __forceinline__ float gather_edge(const float* __restrict__ Xsrc,
                                             const int* __restrict__ order,
                                             const int* __restrict__ Dv,
                                             const int* __restrict__ locCnt,
                                             const int* __restrict__ locList,
                                             int b, int e, int c) {
    float acc = 0.f;
    if (e < N_) {
        int cnt = Dv[b * N_ + e];
        const int* o = order + ((size_t)(b * N_ + e)) * N_;
        for (int t = 0; t < cnt; ++t)
            acc += Xsrc[((size_t)(b * N_ + o[t])) * C_ + c];
    } else {
        int le = e - N_;
        int cnt = locCnt[le];
        const int* L = locList + le * 32;
        for (int t = 0; t < cnt; ++t)
            acc += Xsrc[((size_t)(b * N_ + L[t])) * C_ + c];
    }
    return acc;
}

// ---------------- E init: E0 = W_ev @ X ----------------
__global__ void k_einit(const float* __restrict__ Xsrc, float* __restrict__ Edst,
                        const int* __restrict__ order, const int* __restrict__ Dv,
                        const int* __restrict__ locCnt, const int* __restrict__ locList,
                        const float* __restrict__ recipDE) {
    int be = blockIdx.x;
    int b = be / ET_, e = be % ET_;
    int c = threadIdx.x;
    float acc = gather_edge(Xsrc, order, Dv, locCnt, locList, b, e, c);
    Edst[(size_t)be * C_ + c] = recipDE[be] * acc;
}

// ---------------- fused diffusion step (node + edge update) ----------------
__global__ void k_step(const float* __restrict__ Xsrc, const float* __restrict__ Esrc,
                       float* __restrict__ Xdst, float* __restrict__ Edst,
                       const int* __restrict__ order, const int* __restrict__ Dv,
                       const int* __restrict__ locCnt, const int* __restrict__ locList,
                       const int* __restrict__ nodeCnt, const int* __restrict__ nodeList,
                       const float* __restrict__ recipDV, const float* __restrict__ recipDE) {
    int bid = blockIdx.x;
    int c = threadIdx.x;
    if (bid < B_ * N_) {
        // X_new = 0.95*X + 0.05 * (1/DV) * sum_{e in list(n)} E[e]
        int rn = bid;
        int b = rn >> 10;
        int cnt = nodeCnt[rn];
        const int* lst = nodeList + (size_t)rn * CAP_;
        float acc = 0.f;
        for (int t = 0; t < cnt; ++t) {
            int e = lst[t];
            acc += Esrc[((size_t)(b * ET_ + e)) * C_ + c];
        }
        size_t o = (size_t)rn * C_ + c;
        Xdst[o] = 0.95f * Xsrc[o] + 0.05f * recipDV[rn] * acc;
    } else {
        // E_new = 0.1*E + 0.9 * (1/DE) * sum_{j in mem(e)} X[j]
        int be = bid - B_ * N_;
        int b = be / ET_, e = be % ET_;
        float acc = gather_edge(Xsrc, order, Dv, locCnt, locList, b, e, c);
        size_t o = (size_t)be * C_ + c;
        Edst[o] = 0.1f * Esrc[o] + 0.9f * recipDE[be] * acc;
    }
}

// ---------------- Z = Z + relu(Z @ W^T + bias), per row ----------------
__global__ void k_transform(float* __restrict__ Z, const float* __restrict__ W,
                            const float* __restrict__ bias, int rows) {
    int r = blockIdx.x;
    if (r >= rows) return;
    int c = threadIdx.x;
    __shared__ __align__(16) float z[C_];
    z[c] = Z[(size_t)r * C_ + c];
    __syncthreads();
    float acc = bias[c];
    const float4* w4 = (const float4*)(W + (size_t)c * C_);
    const float4* z4 = (const float4*)z;
    #pragma unroll
    for (int k = 0; k < 32; ++k) {
        float4 w = w4[k], zz = z4[k];
        acc += w.x * zz.x + w.y * zz.y + w.z * zz.z + w.w * zz.w;
    }
    Z[(size_t)r * C_ + c] = z[c] + fmaxf(acc, 0.f);
}

// ---------------- bn_nodes: per-position norm over (B, C) ----------------
__global__ void k_bn(float* __restrict__ Z, int P) {
    int pos = blockIdx.x;
    int t = threadIdx.x; // 256
    __shared__ float red[256];
    float v[4];
    #pragma unroll
    for (int q = 0; q < 4; ++q) {
        int f = t + q * 256;
        int b = f >> 7, c = f & 127;
        v[q] = Z[((size_t)(b * P + pos)) * C_ + c];
    }
    float s = v[0] + v[1] + v[2] + v[3];
    red[t] = s;
    __syncthreads();
    for (int off = 128; off > 0; off >>= 1) {
        if (t < off) red[t] += red[t + off];
        __syncthreads();
    }
    float m = red[0] * (1.0f / 1024.0f);
    __syncthreads();
    float s2 = 0.f;
    #pragma unroll
    for (int q = 0; q < 4; ++q) { float d = v[q] - m; s2 += d * d; }
    red[t] = s2;
    __syncthreads();
    for (int off = 128; off > 0; off >>= 1) {
        if (t < off) red[t] += red[t + off];
        __syncthreads();
    }
    float rstd = rsqrtf(red[0] * (1.0f / 1024.0f) + 1e-5f);
    #pragma unroll
    for (int q = 0; q < 4; ++q) {
        int f = t + q * 256;
        int b = f >> 7, c = f & 127;
        Z[((size_t)(b * P + pos)) * C_ + c] = (v[q] - m) * rstd;
    }
}

// ---------------- final per-channel stats over (B,N) ----------------
__global__ void k_finstats(const float* __restrict__ Xf, float* __restrict__ stats) {
    int c = blockIdx.x;  // 128
    int t = threadIdx.x; // 256
    __shared__ float rs[256], rs2[256];
    float s = 0.f, s2 = 0.f;
    for (int r = t; r < B_ * N_; r += 256) {
        float x = Xf[(size_t)r * C_ + c];
        s += x;
        s2 += x * x;
    }
    rs[t] = s; rs2[t] = s2;
    __syncthreads();
    for (int off = 128; off > 0; off >>= 1) {
        if (t < off) { rs[t] += rs[t + off]; rs2[t] += rs2[t + off]; }
        __syncthreads();
    }
    if (t == 0) {
        float m = rs[0] / (float)(B_ * N_);
        float var = rs2[0] / (float)(B_ * N_) - m * m;
        stats[c] = m;
        stats[C_ + c] = rsqrtf(var + 1e-5f);
    }
}

__global__ void k_finapply(const float* __restrict__ Xf, const float* __restrict__ Xin,
                           const float* __restrict__ stats, const float* __restrict__ bnw,
                           const float* __restrict__ bnb, float* __restrict__ out) {
    size_t i = (size_t)blockIdx.x * blockDim.x + threadIdx.x;
    if (i >= (size_t)B_ * N_ * C_) return;
    int c = (int)(i & (C_ - 1));
    float x = Xf[i];
    float xn = (x - stats[c]) * stats[C_ + c] * bnw[c] + bnb[c];
    out[i] = fmaxf(xn, 0.f) + Xin[i];
}

extern "C" void kernel_launch(void* const* d_in, const int* in_sizes, int n_in,
                              void* d_out, int out_size, void* d_ws, size_t ws_size,
                              hipStream_t stream) {
    const float* Xin = (const float*)d_in[0];
    const float* localH = (const float*)d_in[1];
    const float* tv_w = (const float*)d_in[2];
    const float* tv_b = (const float*)d_in[3];
    const float* te_w = (const float*)d_in[4];
    const float* te_b = (const float*)d_in[5];
    const float* bn_w = (const float*)d_in[6];
    const float* bn_b = (const float*)d_in[7];
    float* out = (float*)d_out;

    char* base = (char*)d_ws;
    size_t off = 0;
    auto alloc = [&](size_t bytes) -> void* {
        void* p = base + off;
        off = (off + bytes + 255) & ~(size_t)255;
        return p;
    };
    int* order = (int*)alloc((size_t)B_ * N_ * N_ * 4);
    float* x2 = (float*)alloc((size_t)B_ * N_ * 4);
    int* Dv = (int*)alloc((size_t)B_ * N_ * 4);
    int* nodeCnt = (int*)alloc((size_t)B_ * N_ * 4);
    int* nodeList = (int*)alloc((size_t)B_ * N_ * CAP_ * 4);
    float* recipDV = (float*)alloc((size_t)B_ * N_ * 4);
    float* recipDE = (float*)alloc((size_t)B_ * ET_ * 4);
    int* locCnt = (int*)alloc(256 * 4);
    int* locList = (int*)alloc((size_t)EL_ * 32 * 4);
    float* X0 = (float*)alloc((size_t)B_ * N_ * C_ * 4);
    float* X1 = (float*)alloc((size_t)B_ * N_ * C_ * 4);
    float* E0 = (float*)alloc((size_t)B_ * ET_ * C_ * 4);
    float* E1 = (float*)alloc((size_t)B_ * ET_ * C_ * 4);
    float* stats = (float*)alloc(2 * C_ * 4);
    if (off > ws_size) return; // workspace too small — fail loudly via validation

    hipMemsetAsync(Dv, 0, (size_t)B_ * N_ * 4, stream);
    hipMemsetAsync(nodeCnt, 0, (size_t)B_ * N_ * 4, stream);
    hipMemcpyAsync(X0, Xin, (size_t)B_ * N_ * C_ * 4, hipMemcpyDeviceToDevice, stream);

    k_x2<<<B_ * N_ / 4, 256, 0, stream>>>(Xin, x2);
    k_distsort<<<B_ * N_, 256, 0, stream>>>(Xin, x2, order);
    k_h1deg<<<B_ * N_ / 256, 256, 0, stream>>>(order, Dv);
    k_locbuild<<<1, 256, 0, stream>>>(localH, locCnt, locList);
    k_edgefill<<<(B_ * ET_ + 255) / 256, 256, 0, stream>>>(order, Dv, locCnt, locList,
                                                           nodeCnt, nodeList, recipDE);
    k_sortlists<<<B_ * N_ / 256, 256, 0, stream>>>(nodeCnt, nodeList, recipDV);
    k_einit<<<B_ * ET_, 128, 0, stream>>>(X0, E0, order, Dv, locCnt, locList, recipDE);

    float* Xc = X0; float* Xn = X1; float* Ec = E0; float* En = E1;
    for (int i = 0; i < 40; ++i) {
        if (i % 20 == 0) {
            k_transform<<<B_ * N_, 128, 0, stream>>>(Xc, tv_w, tv_b, B_ * N_);
            k_transform<<<B_ * ET_, 128, 0, stream>>>(Ec, te_w, te_b, B_ * ET_);
            k_bn<<<N_, 256, 0, stream>>>(Xc, N_);
            k_bn<<<ET_, 256, 0, stream>>>(Ec, ET_);
        }
        k_step<<<B_ * N_ + B_ * ET_, 128, 0, stream>>>(Xc, Ec, Xn, En, order, Dv, locCnt,
                                                       locList, nodeCnt, nodeList, recipDV,
                                                       recipDE);
        float* t;
        t = Xc; Xc = Xn; Xn = t;
        t = Ec; Ec = En; En = t;
    }

    k_finstats<<<C_, 256, 0, stream>>>(Xc, stats);
    k_finapply<<<(B_ * N_ * C_ + 255) / 256, 256, 0, stream>>>(Xc, Xin, stats, bn_w, bn_b, out);
}

// Round 2
// 4450.135 us; speedup vs baseline: 1.4811x; 1.4811x over previous
//
#include <hip/hip_runtime.h>
#include <hip/hip_bf16.h>

constexpr int B_ = 8;
constexpr int N_ = 1024;      // nodes
constexpr int C_ = 128;       // channels
constexpr int EL_ = 196;      // local edges
constexpr int ET_ = N_ + EL_; // 1220 total edges
constexpr int KNN_ = 11;      // k+1
constexpr int CAP_ = 256;     // per-node edge-list capacity

// ---------------- x2 = sum(x*x) per row ----------------
__global__ void k_x2(const float* __restrict__ X, float* __restrict__ x2) {
    int row = blockIdx.x * 4 + (threadIdx.x >> 6);
    int lane = threadIdx.x & 63;
    const float* xr = X + (size_t)row * C_;
    float a = xr[lane], b = xr[lane + 64];
    float s = a * a + b * b;
    #pragma unroll
    for (int off = 32; off > 0; off >>= 1) s += __shfl_down(s, off, 64);
    if (lane == 0) x2[row] = s;
}

__device__ __forceinline__ bool lessKI(float da, int ia, float db, int ib) {
    return (da < db) || (da == db && ia < ib);
}

// ---------------- distances + stable argsort per row ----------------
__global__ __launch_bounds__(256) void k_distsort(const float* __restrict__ X,
                                                  const float* __restrict__ x2,
                                                  int* __restrict__ order) {
    __shared__ float sd[N_];
    __shared__ int si[N_];
    __shared__ __align__(16) float xn[C_];
    int rn = blockIdx.x;           // 0..B*N-1
    int b = rn >> 10, n = rn & 1023;
    int tid = threadIdx.x;
    if (tid < C_) xn[tid] = X[((size_t)(b * N_ + n)) * C_ + tid];
    __syncthreads();
    float x2n = x2[b * N_ + n];
    const float4* xn4 = (const float4*)xn;
    #pragma unroll
    for (int q = 0; q < 4; ++q) {
        int m = tid + q * 256;
        const float4* xm4 = (const float4*)(X + ((size_t)(b * N_ + m)) * C_);
        float dot = 0.f;
        #pragma unroll
        for (int k = 0; k < 32; ++k) {
            float4 a = xm4[k], c = xn4[k];
            dot += a.x * c.x + a.y * c.y + a.z * c.z + a.w * c.w;
        }
        sd[m] = x2n - 2.f * dot + x2[b * N_ + m];
        si[m] = m;
    }
    // bitonic sort ascending by (dist, idx)  == stable argsort
    for (int ksz = 2; ksz <= N_; ksz <<= 1) {
        for (int j = ksz >> 1; j > 0; j >>= 1) {
            __syncthreads();
            for (int l = tid; l < N_; l += 256) {
                int p = l ^ j;
                if (p > l) {
                    float dl = sd[l], dp = sd[p];
                    int il = si[l], ip = si[p];
                    bool asc = ((l & ksz) == 0);
                    bool dosw = asc ? lessKI(dp, ip, dl, il) : lessKI(dl, il, dp, ip);
                    if (dosw) { sd[l] = dp; sd[p] = dl; si[l] = ip; si[p] = il; }
                }
            }
        }
    }
    __syncthreads();
    for (int l = tid; l < N_; l += 256)
        order[(size_t)rn * N_ + l] = si[l];
}

// ---------------- H1 node degrees (top-11), thread per (row,t) ----------------
__global__ void k_h1deg(const int* __restrict__ order, int* __restrict__ Dv) {
    int idx = blockIdx.x * blockDim.x + threadIdx.x;
    if (idx >= B_ * N_ * KNN_) return;
    int rn = idx / KNN_;
    int t = idx - rn * KNN_;
    int b = rn >> 10;
    atomicAdd(&Dv[b * N_ + order[(size_t)rn * N_ + t]], 1);
}

// ---------------- local edge member lists: wave per edge, ordered compaction ----
__global__ void k_locbuild(const float* __restrict__ localH, int* __restrict__ locCnt,
                           int* __restrict__ locList) {
    int w = (blockIdx.x * blockDim.x + threadIdx.x) >> 6;
    int lane = threadIdx.x & 63;
    if (w >= EL_) return;
    int le = w;
    int base = 0;
    for (int chunk = 0; chunk < N_ / 64; ++chunk) {
        int n = chunk * 64 + lane;
        bool m = localH[(size_t)n * EL_ + le] != 0.0f;
        unsigned long long mask = __ballot(m);
        if (m) {
            int pos = base + __popcll(mask & ((1ull << lane) - 1ull));
            locList[le * 32 + pos] = n;
        }
        base += __popcll(mask);
    }
    if (lane == 0) locCnt[le] = base;
}

// ---------------- per-edge fill of node->edge lists: wave per edge ----------------
__global__ void k_edgefill(const int* __restrict__ order, const int* __restrict__ Dv,
                           const int* __restrict__ locCnt, const int* __restrict__ locList,
                           int* __restrict__ nodeCnt, int* __restrict__ nodeList,
                           float* __restrict__ recipDE) {
    int w = (blockIdx.x * blockDim.x + threadIdx.x) >> 6;
    int lane = threadIdx.x & 63;
    if (w >= B_ * ET_) return;
    int b = w / ET_, e = w % ET_;
    int cnt;
    const int* src;
    if (e < N_) {
        cnt = Dv[b * N_ + e];
        src = order + ((size_t)(b * N_ + e)) * N_;
    } else {
        cnt = locCnt[e - N_];
        src = locList + (e - N_) * 32;
    }
    for (int t = lane; t < cnt; t += 64) {
        int j = src[t];
        int pos = atomicAdd(&nodeCnt[b * N_ + j], 1);
        if (pos < CAP_) nodeList[((size_t)(b * N_ + j)) * CAP_ + pos] = e;
    }
    if (lane == 0) recipDE[w] = 1.0f / (float)cnt;
}

// ---------------- wave-per-node rank sort (edge ids unique) + recipDV ----------------
__global__ __launch_bounds__(256) void k_sortlists(int* __restrict__ nodeCnt,
                                                   int* __restrict__ nodeList,
                                                   float* __restrict__ recipDV) {
    __shared__ int sl[4][CAP_];
    int w = threadIdx.x >> 6;
    int lane = threadIdx.x & 63;
    int rn = blockIdx.x * 4 + w;
    int cnt = nodeCnt[rn];
    if (cnt > CAP_) cnt = CAP_;
    int* g = nodeList + (size_t)rn * CAP_;
    for (int t = lane; t < cnt; t += 64) sl[w][t] = g[t];
    __syncthreads();
    for (int t = lane; t < cnt; t += 64) {
        int v = sl[w][t];
        int rank = 0;
        for (int j = 0; j < cnt; ++j) rank += (sl[w][j] < v) ? 1 : 0;
        g[rank] = v;
    }
    if (lane == 0) {
        recipDV[rn] = 1.0f / (float)cnt;
        nodeCnt[rn] = cnt;
    }
}

// ---------------- edge gather helper ----------------
__device__ __forceinline__ float gather_edge(const float* __restrict__ Xsrc,
                                             const int* __restrict__ order,
                                             const int* __restrict__ Dv,
                                             const int* __restrict__ locCnt,
                                             const int* __restrict__ locList,
                                             int b, int e, int c) {
    float acc = 0.f;
    if (e < N_) {
        int cnt = Dv[b * N_ + e];
        const int* o = order + ((size_t)(b * N_ + e)) * N_;
        for (int t = 0; t < cnt; ++t)
            acc += Xsrc[((size_t)(b * N_ + o[t])) * C_ + c];
    } else {
        int le = e - N_;
        int cnt = locCnt[le];
        const int* L = locList + le * 32;
        for (int t = 0; t < cnt; ++t)
            acc += Xsrc[((size_t)(b * N_ + L[t])) * C_ + c];
    }
    return acc;
}

// ---------------- E init: E0 = W_ev @ X ----------------
__global__ void k_einit(const float* __restrict__ Xsrc, float* __restrict__ Edst,
                        const int* __restrict__ order, const int* __restrict__ Dv,
                        const int* __restrict__ locCnt, const int* __restrict__ locList,
                        const float* __restrict__ recipDE) {
    int be = blockIdx.x;
    int b = be / ET_, e = be % ET_;
    int c = threadIdx.x;
    float acc = gather_edge(Xsrc, order, Dv, locCnt, locList, b, e, c);
    Edst[(size_t)be * C_ + c] = recipDE[be] * acc;
}

// ---------------- fused diffusion step (node + edge update) ----------------
__global__ void k_step(const float* __restrict__ Xsrc, const float* __restrict__ Esrc,
                       float* __restrict__ Xdst, float* __restrict__ Edst,
                       const int* __restrict__ order, const int* __restrict__ Dv,
                       const int* __restrict__ locCnt, const int* __restrict__ locList,
                       const int* __restrict__ nodeCnt, const int* __restrict__ nodeList,
                       const float* __restrict__ recipDV, const float* __restrict__ recipDE) {
    int bid = blockIdx.x;
    int c = threadIdx.x;
    if (bid < B_ * N_) {
        // X_new = 0.95*X + 0.05 * (1/DV) * sum_{e in list(n)} E[e]
        int rn = bid;
        int b = rn >> 10;
        int cnt = nodeCnt[rn];
        const int* lst = nodeList + (size_t)rn * CAP_;
        float acc = 0.f;
        for (int t = 0; t < cnt; ++t) {
            int e = lst[t];
            acc += Esrc[((size_t)(b * ET_ + e)) * C_ + c];
        }
        size_t o = (size_t)rn * C_ + c;
        Xdst[o] = 0.95f * Xsrc[o] + 0.05f * recipDV[rn] * acc;
    } else {
        // E_new = 0.1*E + 0.9 * (1/DE) * sum_{j in mem(e)} X[j]
        int be = bid - B_ * N_;
        int b = be / ET_, e = be % ET_;
        float acc = gather_edge(Xsrc, order, Dv, locCnt, locList, b, e, c);
        size_t o = (size_t)be * C_ + c;
        Edst[o] = 0.1f * Esrc[o] + 0.9f * recipDE[be] * acc;
    }
}

// ---------------- Z = Z + relu(Z @ W^T + bias), per row ----------------
__global__ void k_transform(float* __restrict__ Z, const float* __restrict__ W,
                            const float* __restrict__ bias, int rows) {
    int r = blockIdx.x;
    if (r >= rows) return;
    int c = threadIdx.x;
    __shared__ __align__(16) float z[C_];
    z[c] = Z[(size_t)r * C_ + c];
    __syncthreads();
    float acc = bias[c];
    const float4* w4 = (const float4*)(W + (size_t)c * C_);
    const float4* z4 = (const float4*)z;
    #pragma unroll
    for (int k = 0; k < 32; ++k) {
        float4 w = w4[k], zz = z4[k];
        acc += w.x * zz.x + w.y * zz.y + w.z * zz.z + w.w * zz.w;
    }
    Z[(size_t)r * C_ + c] = z[c] + fmaxf(acc, 0.f);
}

// ---------------- bn_nodes: per-position norm over (B, C) ----------------
__global__ void k_bn(float* __restrict__ Z, int P) {
    int pos = blockIdx.x;
    int t = threadIdx.x; // 256
    __shared__ float red[256];
    float v[4];
    #pragma unroll
    for (int q = 0; q < 4; ++q) {
        int f = t + q * 256;
        int b = f >> 7, c = f & 127;
        v[q] = Z[((size_t)(b * P + pos)) * C_ + c];
    }
    float s = v[0] + v[1] + v[2] + v[3];
    red[t] = s;
    __syncthreads();
    for (int off = 128; off > 0; off >>= 1) {
        if (t < off) red[t] += red[t + off];
        __syncthreads();
    }
    float m = red[0] * (1.0f / 1024.0f);
    __syncthreads();
    float s2 = 0.f;
    #pragma unroll
    for (int q = 0; q < 4; ++q) { float d = v[q] - m; s2 += d * d; }
    red[t] = s2;
    __syncthreads();
    for (int off = 128; off > 0; off >>= 1) {
        if (t < off) red[t] += red[t + off];
        __syncthreads();
    }
    float rstd = rsqrtf(red[0] * (1.0f / 1024.0f) + 1e-5f);
    #pragma unroll
    for (int q = 0; q < 4; ++q) {
        int f = t + q * 256;
        int b = f >> 7, c = f & 127;
        Z[((size_t)(b * P + pos)) * C_ + c] = (v[q] - m) * rstd;
    }
}

// ---------------- final per-channel stats over (B,N) ----------------
__global__ void k_finstats(const float* __restrict__ Xf, float* __restrict__ stats) {
    int c = blockIdx.x;  // 128
    int t = threadIdx.x; // 256
    __shared__ float rs[256], rs2[256];
    float s = 0.f, s2 = 0.f;
    for (int r = t; r < B_ * N_; r += 256) {
        float x = Xf[(size_t)r * C_ + c];
        s += x;
        s2 += x * x;
    }
    rs[t] = s; rs2[t] = s2;
    __syncthreads();
    for (int off = 128; off > 0; off >>= 1) {
        if (t < off) { rs[t] += rs[t + off]; rs2[t] += rs2[t + off]; }
        __syncthreads();
    }
    if (t == 0) {
        float m = rs[0] / (float)(B_ * N_);
        float var = rs2[0] / (float)(B_ * N_) - m * m;
        stats[c] = m;
        stats[C_ + c] = rsqrtf(var + 1e-5f);
    }
}

__global__ void k_finapply(const float* __restrict__ Xf, const float* __restrict__ Xin,
                           const float* __restrict__ stats, const float* __restrict__ bnw,
                           const float* __restrict__ bnb, float* __restrict__ out) {
    size_t i = (size_t)blockIdx.x * blockDim.x + threadIdx.x;
    if (i >= (size_t)B_ * N_ * C_) return;
    int c = (int)(i & (C_ - 1));
    float x = Xf[i];
    float xn = (x - stats[c]) * stats[C_ + c] * bnw[c] + bnb[c];
    out[i] = fmaxf(xn, 0.f) + Xin[i];
}

extern "C" void kernel_launch(void* const* d_in, const int* in_sizes, int n_in,
                              void* d_out, int out_size, void* d_ws, size_t ws_size,
                              hipStream_t stream) {
    const float* Xin = (const float*)d_in[0];
    const float* localH = (const float*)d_in[1];
    const float* tv_w = (const float*)d_in[2];
    const float* tv_b = (const float*)d_in[3];
    const float* te_w = (const float*)d_in[4];
    const float* te_b = (const float*)d_in[5];
    const float* bn_w = (const float*)d_in[6];
    const float* bn_b = (const float*)d_in[7];
    float* out = (float*)d_out;

    char* base = (char*)d_ws;
    size_t off = 0;
    auto alloc = [&](size_t bytes) -> void* {
        void* p = base + off;
        off = (off + bytes + 255) & ~(size_t)255;
        return p;
    };
    int* order = (int*)alloc((size_t)B_ * N_ * N_ * 4);
    float* x2 = (float*)alloc((size_t)B_ * N_ * 4);
    int* Dv = (int*)alloc((size_t)B_ * N_ * 4);
    int* nodeCnt = (int*)alloc((size_t)B_ * N_ * 4);
    int* nodeList = (int*)alloc((size_t)B_ * N_ * CAP_ * 4);
    float* recipDV = (float*)alloc((size_t)B_ * N_ * 4);
    float* recipDE = (float*)alloc((size_t)B_ * ET_ * 4);
    int* locCnt = (int*)alloc(256 * 4);
    int* locList = (int*)alloc((size_t)EL_ * 32 * 4);
    float* X0 = (float*)alloc((size_t)B_ * N_ * C_ * 4);
    float* X1 = (float*)alloc((size_t)B_ * N_ * C_ * 4);
    float* E0 = (float*)alloc((size_t)B_ * ET_ * C_ * 4);
    float* E1 = (float*)alloc((size_t)B_ * ET_ * C_ * 4);
    float* stats = (float*)alloc(2 * C_ * 4);
    if (off > ws_size) return;

    hipMemsetAsync(Dv, 0, (size_t)B_ * N_ * 4, stream);
    hipMemsetAsync(nodeCnt, 0, (size_t)B_ * N_ * 4, stream);
    hipMemcpyAsync(X0, Xin, (size_t)B_ * N_ * C_ * 4, hipMemcpyDeviceToDevice, stream);

    k_x2<<<B_ * N_ / 4, 256, 0, stream>>>(Xin, x2);
    k_distsort<<<B_ * N_, 256, 0, stream>>>(Xin, x2, order);
    k_h1deg<<<(B_ * N_ * KNN_ + 255) / 256, 256, 0, stream>>>(order, Dv);
    k_locbuild<<<(EL_ * 64 + 255) / 256, 256, 0, stream>>>(localH, locCnt, locList);
    k_edgefill<<<(B_ * ET_ * 64 + 255) / 256, 256, 0, stream>>>(order, Dv, locCnt, locList,
                                                                nodeCnt, nodeList, recipDE);
    k_sortlists<<<B_ * N_ / 4, 256, 0, stream>>>(nodeCnt, nodeList, recipDV);
    k_einit<<<B_ * ET_, 128, 0, stream>>>(X0, E0, order, Dv, locCnt, locList, recipDE);

    float* Xc = X0; float* Xn = X1; float* Ec = E0; float* En = E1;
    for (int i = 0; i < 40; ++i) {
        if (i % 20 == 0) {
            k_transform<<<B_ * N_, 128, 0, stream>>>(Xc, tv_w, tv_b, B_ * N_);
            k_transform<<<B_ * ET_, 128, 0, stream>>>(Ec, te_w, te_b, B_ * ET_);
            k_bn<<<N_, 256, 0, stream>>>(Xc, N_);
            k_bn<<<ET_, 256, 0, stream>>>(Ec, ET_);
        }
        k_step<<<B_ * N_ + B_ * ET_, 128, 0, stream>>>(Xc, Ec, Xn, En, order, Dv, locCnt,
                                                       locList, nodeCnt, nodeList, recipDV,
                                                       recipDE);
        float* t;
        t = Xc; Xc = Xn; Xn = t;
        t = Ec; Ec = En; En = t;
    }

    k_finstats<<<C_, 256, 0, stream>>>(Xc, stats);
    k_finapply<<<(B_ * N_ * C_ + 255) / 256, 256, 0, stream>>>(Xc, Xin, stats, bn_w, bn_b, out);
}

// Round 5
// 3955.453 us; speedup vs baseline: 1.6663x; 1.1251x over previous
//
#include <hip/hip_runtime.h>
#include <hip/hip_bf16.h>

constexpr int B_ = 8;
constexpr int N_ = 1024;      // nodes
constexpr int C_ = 128;       // channels
constexpr int EL_ = 196;      // local edges
constexpr int ET_ = N_ + EL_; // 1220 total edges
constexpr int KNN_ = 11;      // k+1
constexpr int CAP_ = 256;     // per-node edge-list capacity (hub in-degree can reach ~250)
constexpr int CAP2_ = 256;    // per-edge member capacity (= max reverse-kNN in-degree; 128 truncated hubs)

// ---------------- x2 = sum(x*x) per row ----------------
__global__ void k_x2(const float* __restrict__ X, float* __restrict__ x2) {
    int row = blockIdx.x * 4 + (threadIdx.x >> 6);
    int lane = threadIdx.x & 63;
    const float* xr = X + (size_t)row * C_;
    float a = xr[lane], b = xr[lane + 64];
    float s = a * a + b * b;
    #pragma unroll
    for (int off = 32; off > 0; off >>= 1) s += __shfl_down(s, off, 64);
    if (lane == 0) x2[row] = s;
}

// ---------------- full distance matrix, 4 rows per block ----------------
__global__ __launch_bounds__(256) void k_dist(const float* __restrict__ X,
                                              const float* __restrict__ x2,
                                              float* __restrict__ D) {
    __shared__ __align__(16) float xs[4][C_];
    int rbase = blockIdx.x * 4;     // global row (b*N+n), 4|N so same b
    int b = rbase >> 10;
    for (int i = threadIdx.x; i < 4 * C_; i += 256)
        xs[i >> 7][i & 127] = X[((size_t)rbase + (i >> 7)) * C_ + (i & 127)];
    __syncthreads();
    float x2r0 = x2[rbase], x2r1 = x2[rbase + 1], x2r2 = x2[rbase + 2], x2r3 = x2[rbase + 3];
    #pragma unroll
    for (int q = 0; q < 4; ++q) {
        int m = threadIdx.x + q * 256;
        const float4* xm4 = (const float4*)(X + ((size_t)(b * N_ + m)) * C_);
        float a0 = 0.f, a1 = 0.f, a2 = 0.f, a3 = 0.f;
        #pragma unroll
        for (int k = 0; k < 32; ++k) {
            float4 a = xm4[k];
            float4 c0 = ((const float4*)xs[0])[k];
            float4 c1 = ((const float4*)xs[1])[k];
            float4 c2 = ((const float4*)xs[2])[k];
            float4 c3 = ((const float4*)xs[3])[k];
            a0 += a.x * c0.x + a.y * c0.y + a.z * c0.z + a.w * c0.w;
            a1 += a.x * c1.x + a.y * c1.y + a.z * c1.z + a.w * c1.w;
            a2 += a.x * c2.x + a.y * c2.y + a.z * c2.z + a.w * c2.w;
            a3 += a.x * c3.x + a.y * c3.y + a.z * c3.z + a.w * c3.w;
        }
        float x2m = x2[b * N_ + m];
        D[((size_t)rbase + 0) * N_ + m] = x2r0 - 2.f * a0 + x2m;
        D[((size_t)rbase + 1) * N_ + m] = x2r1 - 2.f * a1 + x2m;
        D[((size_t)rbase + 2) * N_ + m] = x2r2 - 2.f * a2 + x2m;
        D[((size_t)rbase + 3) * N_ + m] = x2r3 - 2.f * a3 + x2m;
    }
}

// order-preserving (dist, idx) -> u64 key; replicates stable argsort exactly
__device__ __forceinline__ unsigned long long packkey(float d, int col) {
    unsigned u = __float_as_uint(d);
    u ^= (unsigned)(((int)u >> 31) | 0x80000000);
    return ((unsigned long long)u << 32) | (unsigned)col;
}

// ---------------- top-11 per row -> Dv atomics (wave per row) ----------------
__global__ __launch_bounds__(256) void k_top11dv(const float* __restrict__ D,
                                                 int* __restrict__ Dv) {
    int w = (blockIdx.x * 256 + threadIdx.x) >> 6;
    int lane = threadIdx.x & 63;
    if (w >= B_ * N_) return;
    int b = w >> 10;
    const float4* row4 = (const float4*)(D + (size_t)w * N_);
    unsigned long long k[16];
    #pragma unroll
    for (int j = 0; j < 4; ++j) {
        float4 v = row4[j * 64 + lane];
        int c0 = (j * 64 + lane) * 4;
        k[j * 4 + 0] = packkey(v.x, c0 + 0);
        k[j * 4 + 1] = packkey(v.y, c0 + 1);
        k[j * 4 + 2] = packkey(v.z, c0 + 2);
        k[j * 4 + 3] = packkey(v.w, c0 + 3);
    }
    for (int it = 0; it < KNN_; ++it) {
        unsigned long long lm = k[0];
        #pragma unroll
        for (int i = 1; i < 16; ++i) lm = (k[i] < lm) ? k[i] : lm;
        #pragma unroll
        for (int off = 1; off < 64; off <<= 1) {
            unsigned long long o = __shfl_xor(lm, off, 64);
            lm = (o < lm) ? o : lm;
        }
        if (lane == 0) atomicAdd(&Dv[b * N_ + (int)(lm & 0xFFFFFFFFull)], 1);
        #pragma unroll
        for (int i = 0; i < 16; ++i)
            if (k[i] == lm) k[i] = ~0ull;
    }
}

// ---------------- local edge member lists: wave per edge, ordered compaction ----
__global__ void k_locbuild(const float* __restrict__ localH, int* __restrict__ locCnt,
                           int* __restrict__ locList) {
    int w = (blockIdx.x * blockDim.x + threadIdx.x) >> 6;
    int lane = threadIdx.x & 63;
    if (w >= EL_) return;
    int le = w;
    int base = 0;
    for (int chunk = 0; chunk < N_ / 64; ++chunk) {
        int n = chunk * 64 + lane;
        bool m = localH[(size_t)n * EL_ + le] != 0.0f;
        unsigned long long mask = __ballot(m);
        if (m) {
            int pos = base + __popcll(mask & ((1ull << lane) - 1ull));
            locList[le * 32 + pos] = n;
        }
        base += __popcll(mask);
    }
    if (lane == 0) locCnt[le] = base;
}

// ---------------- edge member extraction + node->edge scatter (wave/edge) -------
__global__ __launch_bounds__(256) void k_edgebuild(const float* __restrict__ D,
                                                   const int* __restrict__ Dv,
                                                   const int* __restrict__ locCnt,
                                                   const int* __restrict__ locList,
                                                   int* __restrict__ edgeMem,
                                                   int* __restrict__ nodeCnt,
                                                   int* __restrict__ nodeList,
                                                   float* __restrict__ recipDE) {
    int w = (blockIdx.x * 256 + threadIdx.x) >> 6;
    int lane = threadIdx.x & 63;
    if (w >= B_ * ET_) return;
    int b = w / ET_, e = w - b * ET_;
    if (e < N_) {
        int rn = b * N_ + e;
        int full = Dv[rn];
        int m = full < CAP2_ ? full : CAP2_;
        const float4* row4 = (const float4*)(D + (size_t)rn * N_);
        unsigned long long k[16];
        #pragma unroll
        for (int j = 0; j < 4; ++j) {
            float4 v = row4[j * 64 + lane];
            int c0 = (j * 64 + lane) * 4;
            k[j * 4 + 0] = packkey(v.x, c0 + 0);
            k[j * 4 + 1] = packkey(v.y, c0 + 1);
            k[j * 4 + 2] = packkey(v.z, c0 + 2);
            k[j * 4 + 3] = packkey(v.w, c0 + 3);
        }
        for (int it = 0; it < m; ++it) {
            unsigned long long lm = k[0];
            #pragma unroll
            for (int i = 1; i < 16; ++i) lm = (k[i] < lm) ? k[i] : lm;
            #pragma unroll
            for (int off = 1; off < 64; off <<= 1) {
                unsigned long long o = __shfl_xor(lm, off, 64);
                lm = (o < lm) ? o : lm;
            }
            int idx = (int)(lm & 0xFFFFFFFFull);
            if (lane == 0) {
                edgeMem[(size_t)rn * CAP2_ + it] = idx;
                int pos = atomicAdd(&nodeCnt[b * N_ + idx], 1);
                if (pos < CAP_) nodeList[((size_t)(b * N_ + idx)) * CAP_ + pos] = e;
            }
            #pragma unroll
            for (int i = 0; i < 16; ++i)
                if (k[i] == lm) k[i] = ~0ull;
        }
        if (lane == 0) recipDE[w] = 1.0f / (float)full;
    } else {
        int le = e - N_;
        int cnt = locCnt[le];
        for (int t = lane; t < cnt; t += 64) {
            int j = locList[le * 32 + t];
            int pos = atomicAdd(&nodeCnt[b * N_ + j], 1);
            if (pos < CAP_) nodeList[((size_t)(b * N_ + j)) * CAP_ + pos] = e;
        }
        if (lane == 0) recipDE[w] = 1.0f / (float)cnt;
    }
}

// ---------------- wave-per-node rank sort (edge ids unique) + recipDV ----------
__global__ __launch_bounds__(256) void k_sortlists(int* __restrict__ nodeCnt,
                                                   int* __restrict__ nodeList,
                                                   float* __restrict__ recipDV) {
    __shared__ int sl[4][CAP_];
    int w = threadIdx.x >> 6;
    int lane = threadIdx.x & 63;
    int rn = blockIdx.x * 4 + w;
    int cnt = nodeCnt[rn];
    if (cnt > CAP_) cnt = CAP_;
    int* g = nodeList + (size_t)rn * CAP_;
    for (int t = lane; t < cnt; t += 64) sl[w][t] = g[t];
    __syncthreads();
    for (int t = lane; t < cnt; t += 64) {
        int v = sl[w][t];
        int rank = 0;
        for (int j = 0; j < cnt; ++j) rank += (sl[w][j] < v) ? 1 : 0;
        g[rank] = v;
    }
    if (lane == 0) {
        recipDV[rn] = 1.0f / (float)cnt;
        nodeCnt[rn] = cnt;
    }
}

// ---------------- edge gather (float2 per lane, wave per row) ----------------
__device__ __forceinline__ float2 gather_edge2(const float* __restrict__ Xsrc,
                                               const int* __restrict__ edgeMem,
                                               const int* __restrict__ Dv,
                                               const int* __restrict__ locCnt,
                                               const int* __restrict__ locList,
                                               int b, int e, int lane) {
    const int* src;
    int cnt;
    if (e < N_) {
        int rn = b * N_ + e;
        cnt = Dv[rn];
        if (cnt > CAP2_) cnt = CAP2_;
        src = edgeMem + (size_t)rn * CAP2_;
    } else {
        cnt = locCnt[e - N_];
        src = locList + (e - N_) * 32;
    }
    float2 acc = make_float2(0.f, 0.f);
    for (int t = 0; t < cnt; ++t) {
        int j = src[t];
        float2 v = *(const float2*)(Xsrc + ((size_t)(b * N_ + j)) * C_ + 2 * lane);
        acc.x += v.x;
        acc.y += v.y;
    }
    return acc;
}

// ---------------- E init: E0 = W_ev @ X (wave per edge-row) ----------------
__global__ void k_einit(const float* __restrict__ Xsrc, float* __restrict__ Edst,
                        const int* __restrict__ edgeMem, const int* __restrict__ Dv,
                        const int* __restrict__ locCnt, const int* __restrict__ locList,
                        const float* __restrict__ recipDE) {
    int w = (blockIdx.x * blockDim.x + threadIdx.x) >> 6;
    int lane = threadIdx.x & 63;
    if (w >= B_ * ET_) return;
    int b = w / ET_, e = w - b * ET_;
    float2 acc = gather_edge2(Xsrc, edgeMem, Dv, locCnt, locList, b, e, lane);
    float r = recipDE[w];
    *(float2*)(Edst + (size_t)w * C_ + 2 * lane) = make_float2(r * acc.x, r * acc.y);
}

// ---------------- fused diffusion step: wave per row ----------------
__global__ void k_step(const float* __restrict__ Xsrc, const float* __restrict__ Esrc,
                       float* __restrict__ Xdst, float* __restrict__ Edst,
                       const int* __restrict__ edgeMem, const int* __restrict__ Dv,
                       const int* __restrict__ locCnt, const int* __restrict__ locList,
                       const int* __restrict__ nodeCnt, const int* __restrict__ nodeList,
                       const float* __restrict__ recipDV, const float* __restrict__ recipDE) {
    int rid = blockIdx.x * 2 + (threadIdx.x >> 6);
    int lane = threadIdx.x & 63;
    if (rid < B_ * N_) {
        int rn = rid;
        int b = rn >> 10;
        int cnt = nodeCnt[rn];
        const int* lst = nodeList + (size_t)rn * CAP_;
        float2 acc = make_float2(0.f, 0.f);
        for (int t = 0; t < cnt; ++t) {
            int e = lst[t];
            float2 v = *(const float2*)(Esrc + ((size_t)(b * ET_ + e)) * C_ + 2 * lane);
            acc.x += v.x;
            acc.y += v.y;
        }
        size_t o = (size_t)rn * C_ + 2 * lane;
        float2 xv = *(const float2*)(Xsrc + o);
        float s = 0.05f * recipDV[rn];
        *(float2*)(Xdst + o) = make_float2(0.95f * xv.x + s * acc.x, 0.95f * xv.y + s * acc.y);
    } else {
        int be = rid - B_ * N_;
        int b = be / ET_, e = be - b * ET_;
        float2 acc = gather_edge2(Xsrc, edgeMem, Dv, locCnt, locList, b, e, lane);
        size_t o = (size_t)be * C_ + 2 * lane;
        float2 ev = *(const float2*)(Esrc + o);
        float s = 0.9f * recipDE[be];
        *(float2*)(Edst + o) = make_float2(0.1f * ev.x + s * acc.x, 0.1f * ev.y + s * acc.y);
    }
}

// ---------------- Z = Z + relu(Z @ W^T + bias), X and E fused ----------------
__global__ void k_transform(float* __restrict__ Xz, float* __restrict__ Ez,
                            const float* __restrict__ tvw, const float* __restrict__ tvb,
                            const float* __restrict__ tew, const float* __restrict__ teb) {
    int r = blockIdx.x;
    float* Z;
    const float *W, *bias;
    if (r < B_ * N_) { Z = Xz + (size_t)r * C_; W = tvw; bias = tvb; }
    else { Z = Ez + (size_t)(r - B_ * N_) * C_; W = tew; bias = teb; }
    int c = threadIdx.x;
    __shared__ __align__(16) float z[C_];
    z[c] = Z[c];
    __syncthreads();
    float acc = bias[c];
    const float4* w4 = (const float4*)(W + (size_t)c * C_);
    const float4* z4 = (const float4*)z;
    #pragma unroll
    for (int k = 0; k < 32; ++k) {
        float4 w = w4[k], zz = z4[k];
        acc += w.x * zz.x + w.y * zz.y + w.z * zz.z + w.w * zz.w;
    }
    Z[c] = z[c] + fmaxf(acc, 0.f);
}

// ---------------- bn_nodes: per-position norm over (B, C), X and E fused -------
__global__ void k_bn(float* __restrict__ Xz, float* __restrict__ Ez) {
    int pos = blockIdx.x;
    float* Z;
    int P;
    if (pos < N_) { Z = Xz; P = N_; }
    else { Z = Ez; P = ET_; pos -= N_; }
    int t = threadIdx.x; // 256
    __shared__ float red[256];
    float v[4];
    #pragma unroll
    for (int q = 0; q < 4; ++q) {
        int f = t + q * 256;
        int b = f >> 7, c = f & 127;
        v[q] = Z[((size_t)(b * P + pos)) * C_ + c];
    }
    float s = v[0] + v[1] + v[2] + v[3];
    red[t] = s;
    __syncthreads();
    for (int off = 128; off > 0; off >>= 1) {
        if (t < off) red[t] += red[t + off];
        __syncthreads();
    }
    float m = red[0] * (1.0f / 1024.0f);
    __syncthreads();
    float s2 = 0.f;
    #pragma unroll
    for (int q = 0; q < 4; ++q) { float d = v[q] - m; s2 += d * d; }
    red[t] = s2;
    __syncthreads();
    for (int off = 128; off > 0; off >>= 1) {
        if (t < off) red[t] += red[t + off];
        __syncthreads();
    }
    float rstd = rsqrtf(red[0] * (1.0f / 1024.0f) + 1e-5f);
    #pragma unroll
    for (int q = 0; q < 4; ++q) {
        int f = t + q * 256;
        int b = f >> 7, c = f & 127;
        Z[((size_t)(b * P + pos)) * C_ + c] = (v[q] - m) * rstd;
    }
}

// ---------------- final per-channel stats over (B,N) ----------------
__global__ void k_finstats(const float* __restrict__ Xf, float* __restrict__ stats) {
    int c = blockIdx.x;  // 128
    int t = threadIdx.x; // 256
    __shared__ float rs[256], rs2[256];
    float s = 0.f, s2 = 0.f;
    for (int r = t; r < B_ * N_; r += 256) {
        float x = Xf[(size_t)r * C_ + c];
        s += x;
        s2 += x * x;
    }
    rs[t] = s; rs2[t] = s2;
    __syncthreads();
    for (int off = 128; off > 0; off >>= 1) {
        if (t < off) { rs[t] += rs[t + off]; rs2[t] += rs2[t + off]; }
        __syncthreads();
    }
    if (t == 0) {
        float m = rs[0] / (float)(B_ * N_);
        float var = rs2[0] / (float)(B_ * N_) - m * m;
        stats[c] = m;
        stats[C_ + c] = rsqrtf(var + 1e-5f);
    }
}

__global__ void k_finapply(const float* __restrict__ Xf, const float* __restrict__ Xin,
                           const float* __restrict__ stats, const float* __restrict__ bnw,
                           const float* __restrict__ bnb, float* __restrict__ out) {
    size_t i = (size_t)blockIdx.x * blockDim.x + threadIdx.x;
    if (i >= (size_t)B_ * N_ * C_) return;
    int c = (int)(i & (C_ - 1));
    float x = Xf[i];
    float xn = (x - stats[c]) * stats[C_ + c] * bnw[c] + bnb[c];
    out[i] = fmaxf(xn, 0.f) + Xin[i];
}

extern "C" void kernel_launch(void* const* d_in, const int* in_sizes, int n_in,
                              void* d_out, int out_size, void* d_ws, size_t ws_size,
                              hipStream_t stream) {
    const float* Xin = (const float*)d_in[0];
    const float* localH = (const float*)d_in[1];
    const float* tv_w = (const float*)d_in[2];
    const float* tv_b = (const float*)d_in[3];
    const float* te_w = (const float*)d_in[4];
    const float* te_b = (const float*)d_in[5];
    const float* bn_w = (const float*)d_in[6];
    const float* bn_b = (const float*)d_in[7];
    float* out = (float*)d_out;

    char* base = (char*)d_ws;
    size_t off = 0;
    auto alloc = [&](size_t bytes) -> void* {
        void* p = base + off;
        off = (off + bytes + 255) & ~(size_t)255;
        return p;
    };
    float* D = (float*)alloc((size_t)B_ * N_ * N_ * 4);
    float* x2 = (float*)alloc((size_t)B_ * N_ * 4);
    int* Dv = (int*)alloc((size_t)B_ * N_ * 4);
    int* nodeCnt = (int*)alloc((size_t)B_ * N_ * 4);
    int* nodeList = (int*)alloc((size_t)B_ * N_ * CAP_ * 4);
    float* recipDV = (float*)alloc((size_t)B_ * N_ * 4);
    float* recipDE = (float*)alloc((size_t)B_ * ET_ * 4);
    int* locCnt = (int*)alloc(256 * 4);
    int* locList = (int*)alloc((size_t)EL_ * 32 * 4);
    int* edgeMem = (int*)alloc((size_t)B_ * N_ * CAP2_ * 4);
    float* X0 = (float*)alloc((size_t)B_ * N_ * C_ * 4);
    float* X1 = (float*)alloc((size_t)B_ * N_ * C_ * 4);
    float* E0 = (float*)alloc((size_t)B_ * ET_ * C_ * 4);
    float* E1 = (float*)alloc((size_t)B_ * ET_ * C_ * 4);
    float* stats = (float*)alloc(2 * C_ * 4);
    if (off > ws_size) return;

    hipMemsetAsync(Dv, 0, (size_t)B_ * N_ * 4, stream);
    hipMemsetAsync(nodeCnt, 0, (size_t)B_ * N_ * 4, stream);
    hipMemcpyAsync(X0, Xin, (size_t)B_ * N_ * C_ * 4, hipMemcpyDeviceToDevice, stream);

    k_x2<<<B_ * N_ / 4, 256, 0, stream>>>(Xin, x2);
    k_dist<<<B_ * N_ / 4, 256, 0, stream>>>(Xin, x2, D);
    k_top11dv<<<B_ * N_ / 4, 256, 0, stream>>>(D, Dv);
    k_locbuild<<<(EL_ * 64 + 255) / 256, 256, 0, stream>>>(localH, locCnt, locList);
    k_edgebuild<<<(B_ * ET_ + 3) / 4, 256, 0, stream>>>(D, Dv, locCnt, locList, edgeMem,
                                                        nodeCnt, nodeList, recipDE);
    k_sortlists<<<B_ * N_ / 4, 256, 0, stream>>>(nodeCnt, nodeList, recipDV);
    k_einit<<<(B_ * ET_ + 1) / 2, 128, 0, stream>>>(X0, E0, edgeMem, Dv, locCnt, locList,
                                                    recipDE);

    float* Xc = X0; float* Xn = X1; float* Ec = E0; float* En = E1;
    const int ROWS = B_ * N_ + B_ * ET_;
    for (int i = 0; i < 40; ++i) {
        if (i % 20 == 0) {
            k_transform<<<ROWS, 128, 0, stream>>>(Xc, Ec, tv_w, tv_b, te_w, te_b);
            k_bn<<<N_ + ET_, 256, 0, stream>>>(Xc, Ec);
        }
        k_step<<<(ROWS + 1) / 2, 128, 0, stream>>>(Xc, Ec, Xn, En, edgeMem, Dv, locCnt,
                                                   locList, nodeCnt, nodeList, recipDV,
                                                   recipDE);
        float* t;
        t = Xc; Xc = Xn; Xn = t;
        t = Ec; Ec = En; En = t;
    }

    k_finstats<<<C_, 256, 0, stream>>>(Xc, stats);
    k_finapply<<<(B_ * N_ * C_ + 255) / 256, 256, 0, stream>>>(Xc, Xin, stats, bn_w, bn_b, out);
}

// Round 6
// 1948.268 us; speedup vs baseline: 3.3830x; 2.0302x over previous
//
#include <hip/hip_runtime.h>
#include <hip/hip_bf16.h>

constexpr int B_ = 8;
constexpr int N_ = 1024;      // nodes
constexpr int C_ = 128;       // channels
constexpr int EL_ = 196;      // local edges
constexpr int ET_ = N_ + EL_; // 1220 total edges
constexpr int KNN_ = 11;      // k+1
constexpr int CAP_ = 512;     // per-node edge-list capacity (u16 entries)
constexpr int CAP2_ = 512;    // per-edge member capacity (max reverse-kNN in-degree > 256!)

// ---------------- x2 = sum(x*x) per row ----------------
__global__ void k_x2(const float* __restrict__ X, float* __restrict__ x2) {
    int row = blockIdx.x * 4 + (threadIdx.x >> 6);
    int lane = threadIdx.x & 63;
    const float* xr = X + (size_t)row * C_;
    float a = xr[lane], b = xr[lane + 64];
    float s = a * a + b * b;
    #pragma unroll
    for (int off = 32; off > 0; off >>= 1) s += __shfl_down(s, off, 64);
    if (lane == 0) x2[row] = s;
}

// ---------------- distance matrix: 4 rows x 4 col-streams per thread ----------
// Row fragments broadcast from LDS (uniform address -> conflict-free); col
// streams are coalesced float4 loads. unroll 4 keeps VGPR ~100 (256 killed occ).
__global__ __launch_bounds__(256) void k_dist(const float* __restrict__ X,
                                              const float* __restrict__ x2,
                                              float* __restrict__ D) {
    __shared__ __align__(16) float xs[4][C_];
    int rbase = blockIdx.x * 4;
    int b = rbase >> 10;
    for (int i = threadIdx.x; i < 4 * C_; i += 256)
        xs[i >> 7][i & 127] = X[((size_t)rbase + (i >> 7)) * C_ + (i & 127)];
    __syncthreads();
    int t = threadIdx.x;
    const float4* Xb4 = (const float4*)(X + (size_t)b * N_ * C_);
    float acc[4][4];
    #pragma unroll
    for (int r = 0; r < 4; ++r)
        #pragma unroll
        for (int j = 0; j < 4; ++j) acc[r][j] = 0.f;
    #pragma unroll 4
    for (int k = 0; k < 32; ++k) {
        float4 r0 = ((const float4*)xs[0])[k];
        float4 r1 = ((const float4*)xs[1])[k];
        float4 r2 = ((const float4*)xs[2])[k];
        float4 r3 = ((const float4*)xs[3])[k];
        #pragma unroll
        for (int j = 0; j < 4; ++j) {
            float4 cv = Xb4[((size_t)(t + j * 256)) * 32 + k];
            acc[0][j] += r0.x * cv.x + r0.y * cv.y + r0.z * cv.z + r0.w * cv.w;
            acc[1][j] += r1.x * cv.x + r1.y * cv.y + r1.z * cv.z + r1.w * cv.w;
            acc[2][j] += r2.x * cv.x + r2.y * cv.y + r2.z * cv.z + r2.w * cv.w;
            acc[3][j] += r3.x * cv.x + r3.y * cv.y + r3.z * cv.z + r3.w * cv.w;
        }
    }
    float x2r[4];
    #pragma unroll
    for (int r = 0; r < 4; ++r) x2r[r] = x2[rbase + r];
    #pragma unroll
    for (int j = 0; j < 4; ++j) {
        int m = t + j * 256;
        float x2m = x2[b * N_ + m];
        #pragma unroll
        for (int r = 0; r < 4; ++r)
            D[((size_t)(rbase + r)) * N_ + m] = x2r[r] - 2.f * acc[r][j] + x2m;
    }
}

// order-preserving (dist, idx) -> u64 key; replicates stable argsort exactly
__device__ __forceinline__ unsigned long long packkey(float d, int col) {
    unsigned u = __float_as_uint(d);
    u ^= (unsigned)(((int)u >> 31) | 0x80000000);
    return ((unsigned long long)u << 32) | (unsigned)col;
}

// ---------------- top-11 per row -> Dv atomics (wave per row) ----------------
__global__ __launch_bounds__(256) void k_top11dv(const float* __restrict__ D,
                                                 int* __restrict__ Dv) {
    int w = (blockIdx.x * 256 + threadIdx.x) >> 6;
    int lane = threadIdx.x & 63;
    if (w >= B_ * N_) return;
    int b = w >> 10;
    const float4* row4 = (const float4*)(D + (size_t)w * N_);
    unsigned long long k[16];
    #pragma unroll
    for (int j = 0; j < 4; ++j) {
        float4 v = row4[j * 64 + lane];
        int c0 = (j * 64 + lane) * 4;
        k[j * 4 + 0] = packkey(v.x, c0 + 0);
        k[j * 4 + 1] = packkey(v.y, c0 + 1);
        k[j * 4 + 2] = packkey(v.z, c0 + 2);
        k[j * 4 + 3] = packkey(v.w, c0 + 3);
    }
    for (int it = 0; it < KNN_; ++it) {
        unsigned long long lm = k[0];
        #pragma unroll
        for (int i = 1; i < 16; ++i) lm = (k[i] < lm) ? k[i] : lm;
        #pragma unroll
        for (int off = 1; off < 64; off <<= 1) {
            unsigned long long o = __shfl_xor(lm, off, 64);
            lm = (o < lm) ? o : lm;
        }
        if (lane == 0) atomicAdd(&Dv[b * N_ + (int)(lm & 0xFFFFFFFFull)], 1);
        #pragma unroll
        for (int i = 0; i < 16; ++i)
            if (k[i] == lm) k[i] = ~0ull;
    }
}

// ---------------- local edge member lists: wave per edge, ordered compaction ----
__global__ void k_locbuild(const float* __restrict__ localH, int* __restrict__ locCnt,
                           unsigned short* __restrict__ locList) {
    int w = (blockIdx.x * blockDim.x + threadIdx.x) >> 6;
    int lane = threadIdx.x & 63;
    if (w >= EL_) return;
    int le = w;
    int base = 0;
    for (int chunk = 0; chunk < N_ / 64; ++chunk) {
        int n = chunk * 64 + lane;
        bool m = localH[(size_t)n * EL_ + le] != 0.0f;
        unsigned long long mask = __ballot(m);
        if (m) {
            int pos = base + __popcll(mask & ((1ull << lane) - 1ull));
            locList[le * 32 + pos] = (unsigned short)n;
        }
        base += __popcll(mask);
    }
    if (lane == 0) locCnt[le] = base;
}

// ---------------- edge member extraction + node->edge scatter (wave/edge) -------
__global__ __launch_bounds__(256) void k_edgebuild(const float* __restrict__ D,
                                                   const int* __restrict__ Dv,
                                                   const int* __restrict__ locCnt,
                                                   const unsigned short* __restrict__ locList,
                                                   unsigned short* __restrict__ edgeMem,
                                                   int* __restrict__ nodeCnt,
                                                   unsigned short* __restrict__ nodeList,
                                                   float* __restrict__ recipDE) {
    int w = (blockIdx.x * 256 + threadIdx.x) >> 6;
    int lane = threadIdx.x & 63;
    if (w >= B_ * ET_) return;
    int b = w / ET_, e = w - b * ET_;
    if (e < N_) {
        int rn = b * N_ + e;
        int full = Dv[rn];
        int m = full < CAP2_ ? full : CAP2_;
        const float4* row4 = (const float4*)(D + (size_t)rn * N_);
        unsigned long long k[16];
        #pragma unroll
        for (int j = 0; j < 4; ++j) {
            float4 v = row4[j * 64 + lane];
            int c0 = (j * 64 + lane) * 4;
            k[j * 4 + 0] = packkey(v.x, c0 + 0);
            k[j * 4 + 1] = packkey(v.y, c0 + 1);
            k[j * 4 + 2] = packkey(v.z, c0 + 2);
            k[j * 4 + 3] = packkey(v.w, c0 + 3);
        }
        for (int it = 0; it < m; ++it) {
            unsigned long long lm = k[0];
            #pragma unroll
            for (int i = 1; i < 16; ++i) lm = (k[i] < lm) ? k[i] : lm;
            #pragma unroll
            for (int off = 1; off < 64; off <<= 1) {
                unsigned long long o = __shfl_xor(lm, off, 64);
                lm = (o < lm) ? o : lm;
            }
            int idx = (int)(lm & 0xFFFFFFFFull);
            if (lane == 0) {
                edgeMem[(size_t)rn * CAP2_ + it] = (unsigned short)idx;
                int pos = atomicAdd(&nodeCnt[b * N_ + idx], 1);
                if (pos < CAP_) nodeList[((size_t)(b * N_ + idx)) * CAP_ + pos] = (unsigned short)e;
            }
            #pragma unroll
            for (int i = 0; i < 16; ++i)
                if (k[i] == lm) k[i] = ~0ull;
        }
        if (lane == 0) recipDE[w] = 1.0f / (float)full;
    } else {
        int le = e - N_;
        int cnt = locCnt[le];
        for (int t = lane; t < cnt; t += 64) {
            int j = locList[le * 32 + t];
            int pos = atomicAdd(&nodeCnt[b * N_ + j], 1);
            if (pos < CAP_) nodeList[((size_t)(b * N_ + j)) * CAP_ + pos] = (unsigned short)e;
        }
        if (lane == 0) recipDE[w] = 1.0f / (float)cnt;
    }
}

// ---------------- wave-per-node rank sort (edge ids unique) + recipDV ----------
__global__ __launch_bounds__(256) void k_sortlists(int* __restrict__ nodeCnt,
                                                   unsigned short* __restrict__ nodeList,
                                                   float* __restrict__ recipDV) {
    __shared__ int sl[4][CAP_];
    int w = threadIdx.x >> 6;
    int lane = threadIdx.x & 63;
    int rn = blockIdx.x * 4 + w;
    int cnt = nodeCnt[rn];
    if (cnt > CAP_) cnt = CAP_;
    unsigned short* g = nodeList + (size_t)rn * CAP_;
    for (int t = lane; t < cnt; t += 64) sl[w][t] = g[t];
    __syncthreads();
    for (int t = lane; t < cnt; t += 64) {
        int v = sl[w][t];
        int rank = 0;
        for (int j = 0; j < cnt; ++j) rank += (sl[w][j] < v) ? 1 : 0;
        g[rank] = (unsigned short)v;
    }
    if (lane == 0) {
        recipDV[rn] = 1.0f / (float)cnt;
        nodeCnt[rn] = cnt;
    }
}

// ---------------- 8-way ILP gather: u16 indices, 8 per uint4 load --------------
__device__ __forceinline__ float2 gather8(const float* __restrict__ base,
                                          const unsigned short* __restrict__ src,
                                          int cnt, int lane) {
    float2 a0 = {0.f, 0.f}, a1 = {0.f, 0.f}, a2 = {0.f, 0.f}, a3 = {0.f, 0.f};
    const float* bl = base + 2 * lane;
    int t = 0;
    for (; t + 8 <= cnt; t += 8) {
        uint4 u = *(const uint4*)(src + t);
        float2 v0 = *(const float2*)(bl + (size_t)(u.x & 0xFFFFu) * C_);
        float2 v1 = *(const float2*)(bl + (size_t)(u.x >> 16) * C_);
        float2 v2 = *(const float2*)(bl + (size_t)(u.y & 0xFFFFu) * C_);
        float2 v3 = *(const float2*)(bl + (size_t)(u.y >> 16) * C_);
        float2 v4 = *(const float2*)(bl + (size_t)(u.z & 0xFFFFu) * C_);
        float2 v5 = *(const float2*)(bl + (size_t)(u.z >> 16) * C_);
        float2 v6 = *(const float2*)(bl + (size_t)(u.w & 0xFFFFu) * C_);
        float2 v7 = *(const float2*)(bl + (size_t)(u.w >> 16) * C_);
        a0.x += v0.x; a0.y += v0.y; a1.x += v1.x; a1.y += v1.y;
        a2.x += v2.x; a2.y += v2.y; a3.x += v3.x; a3.y += v3.y;
        a0.x += v4.x; a0.y += v4.y; a1.x += v5.x; a1.y += v5.y;
        a2.x += v6.x; a2.y += v6.y; a3.x += v7.x; a3.y += v7.y;
    }
    for (; t < cnt; ++t) {
        float2 v = *(const float2*)(bl + (size_t)src[t] * C_);
        a0.x += v.x; a0.y += v.y;
    }
    a0.x += a1.x + a2.x + a3.x;
    a0.y += a1.y + a2.y + a3.y;
    return a0;
}

__device__ __forceinline__ void edge_src(const unsigned short* __restrict__ edgeMem,
                                         const int* __restrict__ Dv,
                                         const int* __restrict__ locCnt,
                                         const unsigned short* __restrict__ locList,
                                         int b, int e,
                                         const unsigned short*& src, int& cnt) {
    if (e < N_) {
        int rn = b * N_ + e;
        cnt = Dv[rn];
        if (cnt > CAP2_) cnt = CAP2_;
        src = edgeMem + (size_t)rn * CAP2_;
    } else {
        cnt = locCnt[e - N_];
        src = locList + (e - N_) * 32;
    }
}

// ---------------- E init: E0 = W_ev @ X (wave per edge-row) ----------------
__global__ void k_einit(const float* __restrict__ Xsrc, float* __restrict__ Edst,
                        const unsigned short* __restrict__ edgeMem, const int* __restrict__ Dv,
                        const int* __restrict__ locCnt, const unsigned short* __restrict__ locList,
                        const float* __restrict__ recipDE) {
    int w = (blockIdx.x * blockDim.x + threadIdx.x) >> 6;
    int lane = threadIdx.x & 63;
    if (w >= B_ * ET_) return;
    int b = w / ET_, e = w - b * ET_;
    const unsigned short* src; int cnt;
    edge_src(edgeMem, Dv, locCnt, locList, b, e, src, cnt);
    float2 acc = gather8(Xsrc + (size_t)b * N_ * C_, src, cnt, lane);
    float r = recipDE[w];
    *(float2*)(Edst + (size_t)w * C_ + 2 * lane) = make_float2(r * acc.x, r * acc.y);
}

// ---------------- fused diffusion step: wave per row ----------------
__global__ void k_step(const float* __restrict__ Xsrc, const float* __restrict__ Esrc,
                       float* __restrict__ Xdst, float* __restrict__ Edst,
                       const unsigned short* __restrict__ edgeMem, const int* __restrict__ Dv,
                       const int* __restrict__ locCnt, const unsigned short* __restrict__ locList,
                       const int* __restrict__ nodeCnt, const unsigned short* __restrict__ nodeList,
                       const float* __restrict__ recipDV, const float* __restrict__ recipDE) {
    int rid = blockIdx.x * 2 + (threadIdx.x >> 6);
    int lane = threadIdx.x & 63;
    if (rid < B_ * N_) {
        int rn = rid;
        int b = rn >> 10;
        float2 acc = gather8(Esrc + (size_t)b * ET_ * C_, nodeList + (size_t)rn * CAP_,
                             nodeCnt[rn], lane);
        size_t o = (size_t)rn * C_ + 2 * lane;
        float2 xv = *(const float2*)(Xsrc + o);
        float s = 0.05f * recipDV[rn];
        *(float2*)(Xdst + o) = make_float2(0.95f * xv.x + s * acc.x, 0.95f * xv.y + s * acc.y);
    } else {
        int be = rid - B_ * N_;
        int b = be / ET_, e = be - b * ET_;
        const unsigned short* src; int cnt;
        edge_src(edgeMem, Dv, locCnt, locList, b, e, src, cnt);
        float2 acc = gather8(Xsrc + (size_t)b * N_ * C_, src, cnt, lane);
        size_t o = (size_t)be * C_ + 2 * lane;
        float2 ev = *(const float2*)(Esrc + o);
        float s = 0.9f * recipDE[be];
        *(float2*)(Edst + o) = make_float2(0.1f * ev.x + s * acc.x, 0.1f * ev.y + s * acc.y);
    }
}

// ---------------- Z = Z + relu(Z @ W^T + bias), X and E fused ----------------
__global__ void k_transform(float* __restrict__ Xz, float* __restrict__ Ez,
                            const float* __restrict__ tvw, const float* __restrict__ tvb,
                            const float* __restrict__ tew, const float* __restrict__ teb) {
    int r = blockIdx.x;
    float* Z;
    const float *W, *bias;
    if (r < B_ * N_) { Z = Xz + (size_t)r * C_; W = tvw; bias = tvb; }
    else { Z = Ez + (size_t)(r - B_ * N_) * C_; W = tew; bias = teb; }
    int c = threadIdx.x;
    __shared__ __align__(16) float z[C_];
    z[c] = Z[c];
    __syncthreads();
    float acc = bias[c];
    const float4* w4 = (const float4*)(W + (size_t)c * C_);
    const float4* z4 = (const float4*)z;
    #pragma unroll
    for (int k = 0; k < 32; ++k) {
        float4 w = w4[k], zz = z4[k];
        acc += w.x * zz.x + w.y * zz.y + w.z * zz.z + w.w * zz.w;
    }
    Z[c] = z[c] + fmaxf(acc, 0.f);
}

// ---------------- bn_nodes: per-position norm over (B, C), X and E fused -------
__global__ void k_bn(float* __restrict__ Xz, float* __restrict__ Ez) {
    int pos = blockIdx.x;
    float* Z;
    int P;
    if (pos < N_) { Z = Xz; P = N_; }
    else { Z = Ez; P = ET_; pos -= N_; }
    int t = threadIdx.x; // 256
    __shared__ float red[256];
    float v[4];
    #pragma unroll
    for (int q = 0; q < 4; ++q) {
        int f = t + q * 256;
        int b = f >> 7, c = f & 127;
        v[q] = Z[((size_t)(b * P + pos)) * C_ + c];
    }
    float s = v[0] + v[1] + v[2] + v[3];
    red[t] = s;
    __syncthreads();
    for (int off = 128; off > 0; off >>= 1) {
        if (t < off) red[t] += red[t + off];
        __syncthreads();
    }
    float m = red[0] * (1.0f / 1024.0f);
    __syncthreads();
    float s2 = 0.f;
    #pragma unroll
    for (int q = 0; q < 4; ++q) { float d = v[q] - m; s2 += d * d; }
    red[t] = s2;
    __syncthreads();
    for (int off = 128; off > 0; off >>= 1) {
        if (t < off) red[t] += red[t + off];
        __syncthreads();
    }
    float rstd = rsqrtf(red[0] * (1.0f / 1024.0f) + 1e-5f);
    #pragma unroll
    for (int q = 0; q < 4; ++q) {
        int f = t + q * 256;
        int b = f >> 7, c = f & 127;
        Z[((size_t)(b * P + pos)) * C_ + c] = (v[q] - m) * rstd;
    }
}

// ---------------- final per-channel stats over (B,N) ----------------
__global__ void k_finstats(const float* __restrict__ Xf, float* __restrict__ stats) {
    int c = blockIdx.x;  // 128
    int t = threadIdx.x; // 256
    __shared__ float rs[256], rs2[256];
    float s = 0.f, s2 = 0.f;
    for (int r = t; r < B_ * N_; r += 256) {
        float x = Xf[(size_t)r * C_ + c];
        s += x;
        s2 += x * x;
    }
    rs[t] = s; rs2[t] = s2;
    __syncthreads();
    for (int off = 128; off > 0; off >>= 1) {
        if (t < off) { rs[t] += rs[t + off]; rs2[t] += rs2[t + off]; }
        __syncthreads();
    }
    if (t == 0) {
        float m = rs[0] / (float)(B_ * N_);
        float var = rs2[0] / (float)(B_ * N_) - m * m;
        stats[c] = m;
        stats[C_ + c] = rsqrtf(var + 1e-5f);
    }
}

__global__ void k_finapply(const float* __restrict__ Xf, const float* __restrict__ Xin,
                           const float* __restrict__ stats, const float* __restrict__ bnw,
                           const float* __restrict__ bnb, float* __restrict__ out) {
    size_t i = (size_t)blockIdx.x * blockDim.x + threadIdx.x;
    if (i >= (size_t)B_ * N_ * C_) return;
    int c = (int)(i & (C_ - 1));
    float x = Xf[i];
    float xn = (x - stats[c]) * stats[C_ + c] * bnw[c] + bnb[c];
    out[i] = fmaxf(xn, 0.f) + Xin[i];
}

extern "C" void kernel_launch(void* const* d_in, const int* in_sizes, int n_in,
                              void* d_out, int out_size, void* d_ws, size_t ws_size,
                              hipStream_t stream) {
    const float* Xin = (const float*)d_in[0];
    const float* localH = (const float*)d_in[1];
    const float* tv_w = (const float*)d_in[2];
    const float* tv_b = (const float*)d_in[3];
    const float* te_w = (const float*)d_in[4];
    const float* te_b = (const float*)d_in[5];
    const float* bn_w = (const float*)d_in[6];
    const float* bn_b = (const float*)d_in[7];
    float* out = (float*)d_out;

    char* base = (char*)d_ws;
    size_t off = 0;
    auto alloc = [&](size_t bytes) -> void* {
        void* p = base + off;
        off = (off + bytes + 255) & ~(size_t)255;
        return p;
    };
    float* D = (float*)alloc((size_t)B_ * N_ * N_ * 4);
    float* x2 = (float*)alloc((size_t)B_ * N_ * 4);
    int* Dv = (int*)alloc((size_t)B_ * N_ * 4);
    int* nodeCnt = (int*)alloc((size_t)B_ * N_ * 4);
    unsigned short* nodeList = (unsigned short*)alloc((size_t)B_ * N_ * CAP_ * 2);
    float* recipDV = (float*)alloc((size_t)B_ * N_ * 4);
    float* recipDE = (float*)alloc((size_t)B_ * ET_ * 4);
    int* locCnt = (int*)alloc(256 * 4);
    unsigned short* locList = (unsigned short*)alloc((size_t)EL_ * 32 * 2);
    unsigned short* edgeMem = (unsigned short*)alloc((size_t)B_ * N_ * CAP2_ * 2);
    float* X0 = (float*)alloc((size_t)B_ * N_ * C_ * 4);
    float* X1 = (float*)alloc((size_t)B_ * N_ * C_ * 4);
    float* E0 = (float*)alloc((size_t)B_ * ET_ * C_ * 4);
    float* E1 = (float*)alloc((size_t)B_ * ET_ * C_ * 4);
    float* stats = (float*)alloc(2 * C_ * 4);
    if (off > ws_size) return;

    hipMemsetAsync(Dv, 0, (size_t)B_ * N_ * 4, stream);
    hipMemsetAsync(nodeCnt, 0, (size_t)B_ * N_ * 4, stream);
    hipMemcpyAsync(X0, Xin, (size_t)B_ * N_ * C_ * 4, hipMemcpyDeviceToDevice, stream);

    k_x2<<<B_ * N_ / 4, 256, 0, stream>>>(Xin, x2);
    k_dist<<<B_ * N_ / 4, 256, 0, stream>>>(Xin, x2, D);
    k_top11dv<<<B_ * N_ / 4, 256, 0, stream>>>(D, Dv);
    k_locbuild<<<(EL_ * 64 + 255) / 256, 256, 0, stream>>>(localH, locCnt, locList);
    k_edgebuild<<<(B_ * ET_ + 3) / 4, 256, 0, stream>>>(D, Dv, locCnt, locList, edgeMem,
                                                        nodeCnt, nodeList, recipDE);
    k_sortlists<<<B_ * N_ / 4, 256, 0, stream>>>(nodeCnt, nodeList, recipDV);
    k_einit<<<(B_ * ET_ + 1) / 2, 128, 0, stream>>>(X0, E0, edgeMem, Dv, locCnt, locList,
                                                    recipDE);

    float* Xc = X0; float* Xn = X1; float* Ec = E0; float* En = E1;
    const int ROWS = B_ * N_ + B_ * ET_;
    for (int i = 0; i < 40; ++i) {
        if (i % 20 == 0) {
            k_transform<<<ROWS, 128, 0, stream>>>(Xc, Ec, tv_w, tv_b, te_w, te_b);
            k_bn<<<N_ + ET_, 256, 0, stream>>>(Xc, Ec);
        }
        k_step<<<(ROWS + 1) / 2, 128, 0, stream>>>(Xc, Ec, Xn, En, edgeMem, Dv, locCnt,
                                                   locList, nodeCnt, nodeList, recipDV,
                                                   recipDE);
        float* t;
        t = Xc; Xc = Xn; Xn = t;
        t = Ec; Ec = En; En = t;
    }

    k_finstats<<<C_, 256, 0, stream>>>(Xc, stats);
    k_finapply<<<(B_ * N_ * C_ + 255) / 256, 256, 0, stream>>>(Xc, Xin, stats, bn_w, bn_b, out);
}

// Round 7
// 1625.038 us; speedup vs baseline: 4.0559x; 1.1989x over previous
//
#include <hip/hip_runtime.h>
#include <hip/hip_bf16.h>

constexpr int B_ = 8;
constexpr int N_ = 1024;      // nodes
constexpr int C_ = 128;       // channels
constexpr int EL_ = 196;      // local edges
constexpr int ET_ = N_ + EL_; // 1220 total edges
constexpr int KNN_ = 11;      // k+1
constexpr int CAP_ = 512;     // per-node edge-list capacity (u16 entries)
constexpr int CAP2_ = 512;    // per-edge member capacity

// ---------------- x2 = sum(x*x) per row ----------------
__global__ void k_x2(const float* __restrict__ X, float* __restrict__ x2) {
    int row = blockIdx.x * 4 + (threadIdx.x >> 6);
    int lane = threadIdx.x & 63;
    const float* xr = X + (size_t)row * C_;
    float a = xr[lane], b = xr[lane + 64];
    float s = a * a + b * b;
    #pragma unroll
    for (int off = 32; off > 0; off >>= 1) s += __shfl_down(s, off, 64);
    if (lane == 0) x2[row] = s;
}

// ---------------- distance matrix: 4 rows x 4 col-streams per thread ----------
__global__ __launch_bounds__(256) void k_dist(const float* __restrict__ X,
                                              const float* __restrict__ x2,
                                              float* __restrict__ D) {
    __shared__ __align__(16) float xs[4][C_];
    int rbase = blockIdx.x * 4;
    int b = rbase >> 10;
    for (int i = threadIdx.x; i < 4 * C_; i += 256)
        xs[i >> 7][i & 127] = X[((size_t)rbase + (i >> 7)) * C_ + (i & 127)];
    __syncthreads();
    int t = threadIdx.x;
    const float4* Xb4 = (const float4*)(X + (size_t)b * N_ * C_);
    float acc[4][4];
    #pragma unroll
    for (int r = 0; r < 4; ++r)
        #pragma unroll
        for (int j = 0; j < 4; ++j) acc[r][j] = 0.f;
    #pragma unroll 4
    for (int k = 0; k < 32; ++k) {
        float4 r0 = ((const float4*)xs[0])[k];
        float4 r1 = ((const float4*)xs[1])[k];
        float4 r2 = ((const float4*)xs[2])[k];
        float4 r3 = ((const float4*)xs[3])[k];
        #pragma unroll
        for (int j = 0; j < 4; ++j) {
            float4 cv = Xb4[((size_t)(t + j * 256)) * 32 + k];
            acc[0][j] += r0.x * cv.x + r0.y * cv.y + r0.z * cv.z + r0.w * cv.w;
            acc[1][j] += r1.x * cv.x + r1.y * cv.y + r1.z * cv.z + r1.w * cv.w;
            acc[2][j] += r2.x * cv.x + r2.y * cv.y + r2.z * cv.z + r2.w * cv.w;
            acc[3][j] += r3.x * cv.x + r3.y * cv.y + r3.z * cv.z + r3.w * cv.w;
        }
    }
    float x2r[4];
    #pragma unroll
    for (int r = 0; r < 4; ++r) x2r[r] = x2[rbase + r];
    #pragma unroll
    for (int j = 0; j < 4; ++j) {
        int m = t + j * 256;
        float x2m = x2[b * N_ + m];
        #pragma unroll
        for (int r = 0; r < 4; ++r)
            D[((size_t)(rbase + r)) * N_ + m] = x2r[r] - 2.f * acc[r][j] + x2m;
    }
}

// monotone map: float total order -> u32 unsigned order
__device__ __forceinline__ unsigned mapdist(float d) {
    unsigned u = __float_as_uint(d);
    return u ^ (unsigned)(((int)u >> 31) | 0x80000000);
}

// wave-parallel top-m selection thresholds for one 1024-wide row.
// theta = dist-bits of the m-th smallest (dist,idx); psi = idx threshold among
// dist==theta ties. Member predicate: md < theta || (md == theta && col <= psi).
// Exactly replicates stable-argsort top-m semantics.
struct SelThresh { unsigned theta; unsigned psi; };

__device__ __forceinline__ SelThresh wave_topm(const unsigned (&md)[16],
                                               const int (&col)[16], int m) {
    unsigned pfx = 0;
    for (int b = 31; b >= 0; --b) {
        unsigned cand = pfx | (1u << b);
        int c = 0;
        #pragma unroll
        for (int i = 0; i < 16; ++i)
            c += __popcll(__ballot(md[i] < cand));
        if (c < m) pfx = cand;
    }
    unsigned theta = pfx;
    int cLt = 0;
    #pragma unroll
    for (int i = 0; i < 16; ++i)
        cLt += __popcll(__ballot(md[i] < theta));
    int t = m - cLt;  // >= 1
    unsigned ppfx = 0;
    for (int b = 9; b >= 0; --b) {
        unsigned cand = ppfx | (1u << b);
        int c = 0;
        #pragma unroll
        for (int i = 0; i < 16; ++i)
            c += __popcll(__ballot(md[i] == theta && (unsigned)col[i] < cand));
        if (c < t) ppfx = cand;
    }
    return {theta, ppfx};
}

__device__ __forceinline__ void load_row16(const float* __restrict__ Drow, int lane,
                                           unsigned (&md)[16], int (&col)[16]) {
    const float4* row4 = (const float4*)Drow;
    #pragma unroll
    for (int j = 0; j < 4; ++j) {
        float4 v = row4[j * 64 + lane];
        int c0 = (j * 64 + lane) * 4;
        md[j * 4 + 0] = mapdist(v.x); col[j * 4 + 0] = c0 + 0;
        md[j * 4 + 1] = mapdist(v.y); col[j * 4 + 1] = c0 + 1;
        md[j * 4 + 2] = mapdist(v.z); col[j * 4 + 2] = c0 + 2;
        md[j * 4 + 3] = mapdist(v.w); col[j * 4 + 3] = c0 + 3;
    }
}

// ---------------- top-11 per row -> Dv atomics (wave per row, radix select) ----
__global__ __launch_bounds__(256) void k_top11dv(const float* __restrict__ D,
                                                 int* __restrict__ Dv) {
    int w = (blockIdx.x * 256 + threadIdx.x) >> 6;
    int lane = threadIdx.x & 63;
    if (w >= B_ * N_) return;
    int b = w >> 10;
    unsigned md[16]; int col[16];
    load_row16(D + (size_t)w * N_, lane, md, col);
    SelThresh st = wave_topm(md, col, KNN_);
    #pragma unroll
    for (int i = 0; i < 16; ++i) {
        bool in = (md[i] < st.theta) || (md[i] == st.theta && (unsigned)col[i] <= st.psi);
        if (in) atomicAdd(&Dv[b * N_ + col[i]], 1);
    }
}

// ---------------- local edge member lists: wave per edge, ordered compaction ----
__global__ void k_locbuild(const float* __restrict__ localH, int* __restrict__ locCnt,
                           unsigned short* __restrict__ locList) {
    int w = (blockIdx.x * blockDim.x + threadIdx.x) >> 6;
    int lane = threadIdx.x & 63;
    if (w >= EL_) return;
    int le = w;
    int base = 0;
    for (int chunk = 0; chunk < N_ / 64; ++chunk) {
        int n = chunk * 64 + lane;
        bool m = localH[(size_t)n * EL_ + le] != 0.0f;
        unsigned long long mask = __ballot(m);
        if (m) {
            int pos = base + __popcll(mask & ((1ull << lane) - 1ull));
            locList[le * 32 + pos] = (unsigned short)n;
        }
        base += __popcll(mask);
    }
    if (lane == 0) locCnt[le] = base;
}

// ------- edge member selection (radix) + ballot-compact + parallel scatter -----
__global__ __launch_bounds__(256) void k_edgebuild(const float* __restrict__ D,
                                                   const int* __restrict__ Dv,
                                                   const int* __restrict__ locCnt,
                                                   const unsigned short* __restrict__ locList,
                                                   unsigned short* __restrict__ edgeMem,
                                                   int* __restrict__ nodeCnt,
                                                   unsigned short* __restrict__ nodeList,
                                                   float* __restrict__ recipDE) {
    int w = (blockIdx.x * 256 + threadIdx.x) >> 6;
    int lane = threadIdx.x & 63;
    if (w >= B_ * ET_) return;
    int b = w / ET_, e = w - b * ET_;
    if (e < N_) {
        int rn = b * N_ + e;
        int full = Dv[rn];
        int m = full < CAP2_ ? full : CAP2_;
        unsigned md[16]; int col[16];
        load_row16(D + (size_t)rn * N_, lane, md, col);
        SelThresh st = wave_topm(md, col, m);
        int base = 0;
        #pragma unroll
        for (int i = 0; i < 16; ++i) {
            bool in = (md[i] < st.theta) || (md[i] == st.theta && (unsigned)col[i] <= st.psi);
            unsigned long long bal = __ballot(in);
            if (in) {
                int pos = base + __popcll(bal & ((1ull << lane) - 1ull));
                edgeMem[(size_t)rn * CAP2_ + pos] = (unsigned short)col[i];
                int p2 = atomicAdd(&nodeCnt[b * N_ + col[i]], 1);
                if (p2 < CAP_) nodeList[((size_t)(b * N_ + col[i])) * CAP_ + p2] = (unsigned short)e;
            }
            base += __popcll(bal);
        }
        if (lane == 0) recipDE[w] = 1.0f / (float)full;
    } else {
        int le = e - N_;
        int cnt = locCnt[le];
        for (int t = lane; t < cnt; t += 64) {
            int j = locList[le * 32 + t];
            int pos = atomicAdd(&nodeCnt[b * N_ + j], 1);
            if (pos < CAP_) nodeList[((size_t)(b * N_ + j)) * CAP_ + pos] = (unsigned short)e;
        }
        if (lane == 0) recipDE[w] = 1.0f / (float)cnt;
    }
}

// ---------------- wave-per-node rank sort (edge ids unique) + recipDV ----------
__global__ __launch_bounds__(256) void k_sortlists(int* __restrict__ nodeCnt,
                                                   unsigned short* __restrict__ nodeList,
                                                   float* __restrict__ recipDV) {
    __shared__ int sl[4][CAP_];
    int w = threadIdx.x >> 6;
    int lane = threadIdx.x & 63;
    int rn = blockIdx.x * 4 + w;
    int cnt = nodeCnt[rn];
    if (cnt > CAP_) cnt = CAP_;
    unsigned short* g = nodeList + (size_t)rn * CAP_;
    for (int t = lane; t < cnt; t += 64) sl[w][t] = g[t];
    __syncthreads();
    for (int t = lane; t < cnt; t += 64) {
        int v = sl[w][t];
        int rank = 0;
        for (int j = 0; j < cnt; ++j) rank += (sl[w][j] < v) ? 1 : 0;
        g[rank] = (unsigned short)v;
    }
    if (lane == 0) {
        recipDV[rn] = 1.0f / (float)cnt;
        nodeCnt[rn] = cnt;
    }
}

// ---------------- 16-way ILP gather: u16 indices, 8 per uint4 load -------------
__device__ __forceinline__ float2 gather16(const float* __restrict__ base,
                                           const unsigned short* __restrict__ src,
                                           int cnt, int lane) {
    float2 a0 = {0.f, 0.f}, a1 = {0.f, 0.f}, a2 = {0.f, 0.f}, a3 = {0.f, 0.f};
    const float* bl = base + 2 * lane;
    int t = 0;
    for (; t + 16 <= cnt; t += 16) {
        uint4 u0 = *(const uint4*)(src + t);
        uint4 u1 = *(const uint4*)(src + t + 8);
        float2 v0 = *(const float2*)(bl + (size_t)(u0.x & 0xFFFFu) * C_);
        float2 v1 = *(const float2*)(bl + (size_t)(u0.x >> 16) * C_);
        float2 v2 = *(const float2*)(bl + (size_t)(u0.y & 0xFFFFu) * C_);
        float2 v3 = *(const float2*)(bl + (size_t)(u0.y >> 16) * C_);
        float2 v4 = *(const float2*)(bl + (size_t)(u0.z & 0xFFFFu) * C_);
        float2 v5 = *(const float2*)(bl + (size_t)(u0.z >> 16) * C_);
        float2 v6 = *(const float2*)(bl + (size_t)(u0.w & 0xFFFFu) * C_);
        float2 v7 = *(const float2*)(bl + (size_t)(u0.w >> 16) * C_);
        float2 w0 = *(const float2*)(bl + (size_t)(u1.x & 0xFFFFu) * C_);
        float2 w1 = *(const float2*)(bl + (size_t)(u1.x >> 16) * C_);
        float2 w2 = *(const float2*)(bl + (size_t)(u1.y & 0xFFFFu) * C_);
        float2 w3 = *(const float2*)(bl + (size_t)(u1.y >> 16) * C_);
        float2 w4 = *(const float2*)(bl + (size_t)(u1.z & 0xFFFFu) * C_);
        float2 w5 = *(const float2*)(bl + (size_t)(u1.z >> 16) * C_);
        float2 w6 = *(const float2*)(bl + (size_t)(u1.w & 0xFFFFu) * C_);
        float2 w7 = *(const float2*)(bl + (size_t)(u1.w >> 16) * C_);
        a0.x += v0.x + v4.x + w0.x + w4.x; a0.y += v0.y + v4.y + w0.y + w4.y;
        a1.x += v1.x + v5.x + w1.x + w5.x; a1.y += v1.y + v5.y + w1.y + w5.y;
        a2.x += v2.x + v6.x + w2.x + w6.x; a2.y += v2.y + v6.y + w2.y + w6.y;
        a3.x += v3.x + v7.x + w3.x + w7.x; a3.y += v3.y + v7.y + w3.y + w7.y;
    }
    for (; t + 8 <= cnt; t += 8) {
        uint4 u = *(const uint4*)(src + t);
        float2 v0 = *(const float2*)(bl + (size_t)(u.x & 0xFFFFu) * C_);
        float2 v1 = *(const float2*)(bl + (size_t)(u.x >> 16) * C_);
        float2 v2 = *(const float2*)(bl + (size_t)(u.y & 0xFFFFu) * C_);
        float2 v3 = *(const float2*)(bl + (size_t)(u.y >> 16) * C_);
        float2 v4 = *(const float2*)(bl + (size_t)(u.z & 0xFFFFu) * C_);
        float2 v5 = *(const float2*)(bl + (size_t)(u.z >> 16) * C_);
        float2 v6 = *(const float2*)(bl + (size_t)(u.w & 0xFFFFu) * C_);
        float2 v7 = *(const float2*)(bl + (size_t)(u.w >> 16) * C_);
        a0.x += v0.x + v4.x; a0.y += v0.y + v4.y;
        a1.x += v1.x + v5.x; a1.y += v1.y + v5.y;
        a2.x += v2.x + v6.x; a2.y += v2.y + v6.y;
        a3.x += v3.x + v7.x; a3.y += v3.y + v7.y;
    }
    for (; t < cnt; ++t) {
        float2 v = *(const float2*)(bl + (size_t)src[t] * C_);
        a0.x += v.x; a0.y += v.y;
    }
    a0.x += a1.x + a2.x + a3.x;
    a0.y += a1.y + a2.y + a3.y;
    return a0;
}

__device__ __forceinline__ void edge_src(const unsigned short* __restrict__ edgeMem,
                                         const int* __restrict__ Dv,
                                         const int* __restrict__ locCnt,
                                         const unsigned short* __restrict__ locList,
                                         int b, int e,
                                         const unsigned short*& src, int& cnt) {
    if (e < N_) {
        int rn = b * N_ + e;
        cnt = Dv[rn];
        if (cnt > CAP2_) cnt = CAP2_;
        src = edgeMem + (size_t)rn * CAP2_;
    } else {
        cnt = locCnt[e - N_];
        src = locList + (e - N_) * 32;
    }
}

// ---------------- E init: E0 = W_ev @ X (wave per edge-row) ----------------
__global__ void k_einit(const float* __restrict__ Xsrc, float* __restrict__ Edst,
                        const unsigned short* __restrict__ edgeMem, const int* __restrict__ Dv,
                        const int* __restrict__ locCnt, const unsigned short* __restrict__ locList,
                        const float* __restrict__ recipDE) {
    int w = (blockIdx.x * blockDim.x + threadIdx.x) >> 6;
    int lane = threadIdx.x & 63;
    if (w >= B_ * ET_) return;
    int b = w / ET_, e = w - b * ET_;
    const unsigned short* src; int cnt;
    edge_src(edgeMem, Dv, locCnt, locList, b, e, src, cnt);
    float2 acc = gather16(Xsrc + (size_t)b * N_ * C_, src, cnt, lane);
    float r = recipDE[w];
    *(float2*)(Edst + (size_t)w * C_ + 2 * lane) = make_float2(r * acc.x, r * acc.y);
}

// ---------------- fused diffusion step: wave per row ----------------
__global__ void k_step(const float* __restrict__ Xsrc, const float* __restrict__ Esrc,
                       float* __restrict__ Xdst, float* __restrict__ Edst,
                       const unsigned short* __restrict__ edgeMem, const int* __restrict__ Dv,
                       const int* __restrict__ locCnt, const unsigned short* __restrict__ locList,
                       const int* __restrict__ nodeCnt, const unsigned short* __restrict__ nodeList,
                       const float* __restrict__ recipDV, const float* __restrict__ recipDE) {
    int rid = blockIdx.x * 2 + (threadIdx.x >> 6);
    int lane = threadIdx.x & 63;
    if (rid < B_ * N_) {
        int rn = rid;
        int b = rn >> 10;
        float2 acc = gather16(Esrc + (size_t)b * ET_ * C_, nodeList + (size_t)rn * CAP_,
                              nodeCnt[rn], lane);
        size_t o = (size_t)rn * C_ + 2 * lane;
        float2 xv = *(const float2*)(Xsrc + o);
        float s = 0.05f * recipDV[rn];
        *(float2*)(Xdst + o) = make_float2(0.95f * xv.x + s * acc.x, 0.95f * xv.y + s * acc.y);
    } else {
        int be = rid - B_ * N_;
        int b = be / ET_, e = be - b * ET_;
        const unsigned short* src; int cnt;
        edge_src(edgeMem, Dv, locCnt, locList, b, e, src, cnt);
        float2 acc = gather16(Xsrc + (size_t)b * N_ * C_, src, cnt, lane);
        size_t o = (size_t)be * C_ + 2 * lane;
        float2 ev = *(const float2*)(Esrc + o);
        float s = 0.9f * recipDE[be];
        *(float2*)(Edst + o) = make_float2(0.1f * ev.x + s * acc.x, 0.1f * ev.y + s * acc.y);
    }
}

// ---------------- Z = Z + relu(Z @ W^T + bias), X and E fused ----------------
__global__ void k_transform(float* __restrict__ Xz, float* __restrict__ Ez,
                            const float* __restrict__ tvw, const float* __restrict__ tvb,
                            const float* __restrict__ tew, const float* __restrict__ teb) {
    int r = blockIdx.x;
    float* Z;
    const float *W, *bias;
    if (r < B_ * N_) { Z = Xz + (size_t)r * C_; W = tvw; bias = tvb; }
    else { Z = Ez + (size_t)(r - B_ * N_) * C_; W = tew; bias = teb; }
    int c = threadIdx.x;
    __shared__ __align__(16) float z[C_];
    z[c] = Z[c];
    __syncthreads();
    float acc = bias[c];
    const float4* w4 = (const float4*)(W + (size_t)c * C_);
    const float4* z4 = (const float4*)z;
    #pragma unroll
    for (int k = 0; k < 32; ++k) {
        float4 w = w4[k], zz = z4[k];
        acc += w.x * zz.x + w.y * zz.y + w.z * zz.z + w.w * zz.w;
    }
    Z[c] = z[c] + fmaxf(acc, 0.f);
}

// ---------------- bn_nodes: per-position norm over (B, C), X and E fused -------
__global__ void k_bn(float* __restrict__ Xz, float* __restrict__ Ez) {
    int pos = blockIdx.x;
    float* Z;
    int P;
    if (pos < N_) { Z = Xz; P = N_; }
    else { Z = Ez; P = ET_; pos -= N_; }
    int t = threadIdx.x; // 256
    __shared__ float red[256];
    float v[4];
    #pragma unroll
    for (int q = 0; q < 4; ++q) {
        int f = t + q * 256;
        int b = f >> 7, c = f & 127;
        v[q] = Z[((size_t)(b * P + pos)) * C_ + c];
    }
    float s = v[0] + v[1] + v[2] + v[3];
    red[t] = s;
    __syncthreads();
    for (int off = 128; off > 0; off >>= 1) {
        if (t < off) red[t] += red[t + off];
        __syncthreads();
    }
    float m = red[0] * (1.0f / 1024.0f);
    __syncthreads();
    float s2 = 0.f;
    #pragma unroll
    for (int q = 0; q < 4; ++q) { float d = v[q] - m; s2 += d * d; }
    red[t] = s2;
    __syncthreads();
    for (int off = 128; off > 0; off >>= 1) {
        if (t < off) red[t] += red[t + off];
        __syncthreads();
    }
    float rstd = rsqrtf(red[0] * (1.0f / 1024.0f) + 1e-5f);
    #pragma unroll
    for (int q = 0; q < 4; ++q) {
        int f = t + q * 256;
        int b = f >> 7, c = f & 127;
        Z[((size_t)(b * P + pos)) * C_ + c] = (v[q] - m) * rstd;
    }
}

// ---------------- final per-channel stats over (B,N) ----------------
__global__ void k_finstats(const float* __restrict__ Xf, float* __restrict__ stats) {
    int c = blockIdx.x;  // 128
    int t = threadIdx.x; // 256
    __shared__ float rs[256], rs2[256];
    float s = 0.f, s2 = 0.f;
    for (int r = t; r < B_ * N_; r += 256) {
        float x = Xf[(size_t)r * C_ + c];
        s += x;
        s2 += x * x;
    }
    rs[t] = s; rs2[t] = s2;
    __syncthreads();
    for (int off = 128; off > 0; off >>= 1) {
        if (t < off) { rs[t] += rs[t + off]; rs2[t] += rs2[t + off]; }
        __syncthreads();
    }
    if (t == 0) {
        float m = rs[0] / (float)(B_ * N_);
        float var = rs2[0] / (float)(B_ * N_) - m * m;
        stats[c] = m;
        stats[C_ + c] = rsqrtf(var + 1e-5f);
    }
}

__global__ void k_finapply(const float* __restrict__ Xf, const float* __restrict__ Xin,
                           const float* __restrict__ stats, const float* __restrict__ bnw,
                           const float* __restrict__ bnb, float* __restrict__ out) {
    size_t i = (size_t)blockIdx.x * blockDim.x + threadIdx.x;
    if (i >= (size_t)B_ * N_ * C_) return;
    int c = (int)(i & (C_ - 1));
    float x = Xf[i];
    float xn = (x - stats[c]) * stats[C_ + c] * bnw[c] + bnb[c];
    out[i] = fmaxf(xn, 0.f) + Xin[i];
}

extern "C" void kernel_launch(void* const* d_in, const int* in_sizes, int n_in,
                              void* d_out, int out_size, void* d_ws, size_t ws_size,
                              hipStream_t stream) {
    const float* Xin = (const float*)d_in[0];
    const float* localH = (const float*)d_in[1];
    const float* tv_w = (const float*)d_in[2];
    const float* tv_b = (const float*)d_in[3];
    const float* te_w = (const float*)d_in[4];
    const float* te_b = (const float*)d_in[5];
    const float* bn_w = (const float*)d_in[6];
    const float* bn_b = (const float*)d_in[7];
    float* out = (float*)d_out;

    char* base = (char*)d_ws;
    size_t off = 0;
    auto alloc = [&](size_t bytes) -> void* {
        void* p = base + off;
        off = (off + bytes + 255) & ~(size_t)255;
        return p;
    };
    float* D = (float*)alloc((size_t)B_ * N_ * N_ * 4);
    float* x2 = (float*)alloc((size_t)B_ * N_ * 4);
    int* Dv = (int*)alloc((size_t)B_ * N_ * 4);
    int* nodeCnt = (int*)alloc((size_t)B_ * N_ * 4);
    unsigned short* nodeList = (unsigned short*)alloc((size_t)B_ * N_ * CAP_ * 2);
    float* recipDV = (float*)alloc((size_t)B_ * N_ * 4);
    float* recipDE = (float*)alloc((size_t)B_ * ET_ * 4);
    int* locCnt = (int*)alloc(256 * 4);
    unsigned short* locList = (unsigned short*)alloc((size_t)EL_ * 32 * 2);
    unsigned short* edgeMem = (unsigned short*)alloc((size_t)B_ * N_ * CAP2_ * 2);
    float* X0 = (float*)alloc((size_t)B_ * N_ * C_ * 4);
    float* X1 = (float*)alloc((size_t)B_ * N_ * C_ * 4);
    float* E0 = (float*)alloc((size_t)B_ * ET_ * C_ * 4);
    float* E1 = (float*)alloc((size_t)B_ * ET_ * C_ * 4);
    float* stats = (float*)alloc(2 * C_ * 4);
    if (off > ws_size) return;

    hipMemsetAsync(Dv, 0, (size_t)B_ * N_ * 4, stream);
    hipMemsetAsync(nodeCnt, 0, (size_t)B_ * N_ * 4, stream);
    hipMemcpyAsync(X0, Xin, (size_t)B_ * N_ * C_ * 4, hipMemcpyDeviceToDevice, stream);

    k_x2<<<B_ * N_ / 4, 256, 0, stream>>>(Xin, x2);
    k_dist<<<B_ * N_ / 4, 256, 0, stream>>>(Xin, x2, D);
    k_top11dv<<<B_ * N_ / 4, 256, 0, stream>>>(D, Dv);
    k_locbuild<<<(EL_ * 64 + 255) / 256, 256, 0, stream>>>(localH, locCnt, locList);
    k_edgebuild<<<(B_ * ET_ + 3) / 4, 256, 0, stream>>>(D, Dv, locCnt, locList, edgeMem,
                                                        nodeCnt, nodeList, recipDE);
    k_sortlists<<<B_ * N_ / 4, 256, 0, stream>>>(nodeCnt, nodeList, recipDV);
    k_einit<<<(B_ * ET_ + 1) / 2, 128, 0, stream>>>(X0, E0, edgeMem, Dv, locCnt, locList,
                                                    recipDE);

    float* Xc = X0; float* Xn = X1; float* Ec = E0; float* En = E1;
    const int ROWS = B_ * N_ + B_ * ET_;
    for (int i = 0; i < 40; ++i) {
        if (i % 20 == 0) {
            k_transform<<<ROWS, 128, 0, stream>>>(Xc, Ec, tv_w, tv_b, te_w, te_b);
            k_bn<<<N_ + ET_, 256, 0, stream>>>(Xc, Ec);
        }
        k_step<<<(ROWS + 1) / 2, 128, 0, stream>>>(Xc, Ec, Xn, En, edgeMem, Dv, locCnt,
                                                   locList, nodeCnt, nodeList, recipDV,
                                                   recipDE);
        float* t;
        t = Xc; Xc = Xn; Xn = t;
        t = Ec; Ec = En; En = t;
    }

    k_finstats<<<C_, 256, 0, stream>>>(Xc, stats);
    k_finapply<<<(B_ * N_ * C_ + 255) / 256, 256, 0, stream>>>(Xc, Xin, stats, bn_w, bn_b, out);
}

// Round 8
// 1173.347 us; speedup vs baseline: 5.6172x; 1.3850x over previous
//
#include <hip/hip_runtime.h>
#include <hip/hip_bf16.h>

constexpr int B_ = 8;
constexpr int N_ = 1024;      // nodes
constexpr int C_ = 128;       // channels
constexpr int EL_ = 196;      // local edges
constexpr int ET_ = N_ + EL_; // 1220 total edges
constexpr int RT_ = N_ + ET_; // 2244 rows (node+edge) per batch
constexpr int KNN_ = 11;      // k+1
constexpr int CAP_ = 512;     // per-node edge-list capacity (u16 entries)
constexpr int CAP2_ = 512;    // per-edge member capacity

// ---------------- x2 = sum(x*x) per row ----------------
__global__ void k_x2(const float* __restrict__ X, float* __restrict__ x2) {
    int row = blockIdx.x * 4 + (threadIdx.x >> 6);
    int lane = threadIdx.x & 63;
    const float* xr = X + (size_t)row * C_;
    float a = xr[lane], b = xr[lane + 64];
    float s = a * a + b * b;
    #pragma unroll
    for (int off = 32; off > 0; off >>= 1) s += __shfl_down(s, off, 64);
    if (lane == 0) x2[row] = s;
}

// ---------------- distance matrix: tiled 128x128 GEMM, batch-per-XCD ----------
// blockIdx&7 = batch (XCD-local X panel); blockIdx>>3 in [0,64): ti=t>>3, tj=t&7.
// LDS k-major with +4 pad; 8x8 register tile per thread (256 thr = 16x16).
__global__ __launch_bounds__(256) void k_dist(const float* __restrict__ X,
                                              const float* __restrict__ x2,
                                              float* __restrict__ D) {
    __shared__ float As[32][132];
    __shared__ float Bs[32][132];
    int b = blockIdx.x & 7;
    int t = blockIdx.x >> 3;
    int ti = t >> 3, tj = t & 7;
    const float* Xb = X + (size_t)b * N_ * C_;
    int tid = threadIdx.x;
    int tx = tid & 15, ty = tid >> 4;
    float acc[8][8];
    #pragma unroll
    for (int i = 0; i < 8; ++i)
        #pragma unroll
        for (int j = 0; j < 8; ++j) acc[i][j] = 0.f;
    for (int kc = 0; kc < 4; ++kc) {
        __syncthreads();
        #pragma unroll
        for (int q = 0; q < 4; ++q) {
            int id = tid + q * 256;
            int r = id >> 3, kk = (id & 7) * 4;
            float4 av = *(const float4*)(Xb + (size_t)(ti * 128 + r) * C_ + kc * 32 + kk);
            As[kk + 0][r] = av.x; As[kk + 1][r] = av.y;
            As[kk + 2][r] = av.z; As[kk + 3][r] = av.w;
            float4 bv = *(const float4*)(Xb + (size_t)(tj * 128 + r) * C_ + kc * 32 + kk);
            Bs[kk + 0][r] = bv.x; Bs[kk + 1][r] = bv.y;
            Bs[kk + 2][r] = bv.z; Bs[kk + 3][r] = bv.w;
        }
        __syncthreads();
        #pragma unroll 8
        for (int k = 0; k < 32; ++k) {
            float a[8], bb[8];
            *(float4*)(a + 0) = *(const float4*)&As[k][ty * 8];
            *(float4*)(a + 4) = *(const float4*)&As[k][ty * 8 + 4];
            *(float4*)(bb + 0) = *(const float4*)&Bs[k][tx * 8];
            *(float4*)(bb + 4) = *(const float4*)&Bs[k][tx * 8 + 4];
            #pragma unroll
            for (int i = 0; i < 8; ++i)
                #pragma unroll
                for (int j = 0; j < 8; ++j) acc[i][j] += a[i] * bb[j];
        }
    }
    float x2r[8], x2c[8];
    #pragma unroll
    for (int i = 0; i < 8; ++i) x2r[i] = x2[b * N_ + ti * 128 + ty * 8 + i];
    #pragma unroll
    for (int j = 0; j < 8; ++j) x2c[j] = x2[b * N_ + tj * 128 + tx * 8 + j];
    #pragma unroll
    for (int i = 0; i < 8; ++i) {
        int m = ti * 128 + ty * 8 + i;
        float* drow = D + ((size_t)(b * N_ + m)) * N_ + tj * 128 + tx * 8;
        float4 o0, o1;
        o0.x = x2r[i] - 2.f * acc[i][0] + x2c[0];
        o0.y = x2r[i] - 2.f * acc[i][1] + x2c[1];
        o0.z = x2r[i] - 2.f * acc[i][2] + x2c[2];
        o0.w = x2r[i] - 2.f * acc[i][3] + x2c[3];
        o1.x = x2r[i] - 2.f * acc[i][4] + x2c[4];
        o1.y = x2r[i] - 2.f * acc[i][5] + x2c[5];
        o1.z = x2r[i] - 2.f * acc[i][6] + x2c[6];
        o1.w = x2r[i] - 2.f * acc[i][7] + x2c[7];
        *(float4*)drow = o0;
        *(float4*)(drow + 4) = o1;
    }
}

// monotone map: float total order -> u32 unsigned order
__device__ __forceinline__ unsigned mapdist(float d) {
    unsigned u = __float_as_uint(d);
    return u ^ (unsigned)(((int)u >> 31) | 0x80000000);
}

// wave-parallel top-m selection thresholds; replicates stable argsort exactly
struct SelThresh { unsigned theta; unsigned psi; };

__device__ __forceinline__ SelThresh wave_topm(const unsigned (&md)[16],
                                               const int (&col)[16], int m) {
    unsigned pfx = 0;
    for (int b = 31; b >= 0; --b) {
        unsigned cand = pfx | (1u << b);
        int c = 0;
        #pragma unroll
        for (int i = 0; i < 16; ++i)
            c += __popcll(__ballot(md[i] < cand));
        if (c < m) pfx = cand;
    }
    unsigned theta = pfx;
    int cLt = 0;
    #pragma unroll
    for (int i = 0; i < 16; ++i)
        cLt += __popcll(__ballot(md[i] < theta));
    int t = m - cLt;  // >= 1
    unsigned ppfx = 0;
    for (int b = 9; b >= 0; --b) {
        unsigned cand = ppfx | (1u << b);
        int c = 0;
        #pragma unroll
        for (int i = 0; i < 16; ++i)
            c += __popcll(__ballot(md[i] == theta && (unsigned)col[i] < cand));
        if (c < t) ppfx = cand;
    }
    return {theta, ppfx};
}

__device__ __forceinline__ void load_row16(const float* __restrict__ Drow, int lane,
                                           unsigned (&md)[16], int (&col)[16]) {
    const float4* row4 = (const float4*)Drow;
    #pragma unroll
    for (int j = 0; j < 4; ++j) {
        float4 v = row4[j * 64 + lane];
        int c0 = (j * 64 + lane) * 4;
        md[j * 4 + 0] = mapdist(v.x); col[j * 4 + 0] = c0 + 0;
        md[j * 4 + 1] = mapdist(v.y); col[j * 4 + 1] = c0 + 1;
        md[j * 4 + 2] = mapdist(v.z); col[j * 4 + 2] = c0 + 2;
        md[j * 4 + 3] = mapdist(v.w); col[j * 4 + 3] = c0 + 3;
    }
}

// ---------------- top-11 per row -> Dv atomics (wave per row, radix select) ----
__global__ __launch_bounds__(256) void k_top11dv(const float* __restrict__ D,
                                                 int* __restrict__ Dv) {
    int w = (blockIdx.x * 256 + threadIdx.x) >> 6;
    int lane = threadIdx.x & 63;
    if (w >= B_ * N_) return;
    int b = w >> 10;
    unsigned md[16]; int col[16];
    load_row16(D + (size_t)w * N_, lane, md, col);
    SelThresh st = wave_topm(md, col, KNN_);
    #pragma unroll
    for (int i = 0; i < 16; ++i) {
        bool in = (md[i] < st.theta) || (md[i] == st.theta && (unsigned)col[i] <= st.psi);
        if (in) atomicAdd(&Dv[b * N_ + col[i]], 1);
    }
}

// ---------------- local edge member lists: wave per edge, ordered compaction ----
__global__ void k_locbuild(const float* __restrict__ localH, int* __restrict__ locCnt,
                           unsigned short* __restrict__ locList) {
    int w = (blockIdx.x * blockDim.x + threadIdx.x) >> 6;
    int lane = threadIdx.x & 63;
    if (w >= EL_) return;
    int le = w;
    int base = 0;
    for (int chunk = 0; chunk < N_ / 64; ++chunk) {
        int n = chunk * 64 + lane;
        bool m = localH[(size_t)n * EL_ + le] != 0.0f;
        unsigned long long mask = __ballot(m);
        if (m) {
            int pos = base + __popcll(mask & ((1ull << lane) - 1ull));
            locList[le * 32 + pos] = (unsigned short)n;
        }
        base += __popcll(mask);
    }
    if (lane == 0) locCnt[le] = base;
}

// ------- edge member selection (radix) + ballot-compact + parallel scatter -----
__global__ __launch_bounds__(256) void k_edgebuild(const float* __restrict__ D,
                                                   const int* __restrict__ Dv,
                                                   const int* __restrict__ locCnt,
                                                   const unsigned short* __restrict__ locList,
                                                   unsigned short* __restrict__ edgeMem,
                                                   int* __restrict__ nodeCnt,
                                                   unsigned short* __restrict__ nodeList,
                                                   float* __restrict__ recipDE) {
    int w = (blockIdx.x * 256 + threadIdx.x) >> 6;
    int lane = threadIdx.x & 63;
    if (w >= B_ * ET_) return;
    int b = w / ET_, e = w - b * ET_;
    if (e < N_) {
        int rn = b * N_ + e;
        int full = Dv[rn];
        int m = full < CAP2_ ? full : CAP2_;
        unsigned md[16]; int col[16];
        load_row16(D + (size_t)rn * N_, lane, md, col);
        SelThresh st = wave_topm(md, col, m);
        int base = 0;
        #pragma unroll
        for (int i = 0; i < 16; ++i) {
            bool in = (md[i] < st.theta) || (md[i] == st.theta && (unsigned)col[i] <= st.psi);
            unsigned long long bal = __ballot(in);
            if (in) {
                int pos = base + __popcll(bal & ((1ull << lane) - 1ull));
                edgeMem[(size_t)rn * CAP2_ + pos] = (unsigned short)col[i];
                int p2 = atomicAdd(&nodeCnt[b * N_ + col[i]], 1);
                if (p2 < CAP_) nodeList[((size_t)(b * N_ + col[i])) * CAP_ + p2] = (unsigned short)e;
            }
            base += __popcll(bal);
        }
        if (lane == 0) recipDE[w] = 1.0f / (float)full;
    } else {
        int le = e - N_;
        int cnt = locCnt[le];
        for (int t = lane; t < cnt; t += 64) {
            int j = locList[le * 32 + t];
            int pos = atomicAdd(&nodeCnt[b * N_ + j], 1);
            if (pos < CAP_) nodeList[((size_t)(b * N_ + j)) * CAP_ + pos] = (unsigned short)e;
        }
        if (lane == 0) recipDE[w] = 1.0f / (float)cnt;
    }
}

// ---------------- wave-per-node rank sort (edge ids unique) + recipDV ----------
__global__ __launch_bounds__(256) void k_sortlists(int* __restrict__ nodeCnt,
                                                   unsigned short* __restrict__ nodeList,
                                                   float* __restrict__ recipDV) {
    __shared__ int sl[4][CAP_];
    int w = threadIdx.x >> 6;
    int lane = threadIdx.x & 63;
    int rn = blockIdx.x * 4 + w;
    int cnt = nodeCnt[rn];
    if (cnt > CAP_) cnt = CAP_;
    unsigned short* g = nodeList + (size_t)rn * CAP_;
    for (int t = lane; t < cnt; t += 64) sl[w][t] = g[t];
    __syncthreads();
    for (int t = lane; t < cnt; t += 64) {
        int v = sl[w][t];
        int rank = 0;
        for (int j = 0; j < cnt; ++j) rank += (sl[w][j] < v) ? 1 : 0;
        g[rank] = (unsigned short)v;
    }
    if (lane == 0) {
        recipDV[rn] = 1.0f / (float)cnt;
        nodeCnt[rn] = cnt;
    }
}

// ---------------- 16-way ILP gather: u16 indices, 8 per uint4 load -------------
__device__ __forceinline__ float2 gather16(const float* __restrict__ base,
                                           const unsigned short* __restrict__ src,
                                           int cnt, int lane) {
    float2 a0 = {0.f, 0.f}, a1 = {0.f, 0.f}, a2 = {0.f, 0.f}, a3 = {0.f, 0.f};
    const float* bl = base + 2 * lane;
    int t = 0;
    for (; t + 16 <= cnt; t += 16) {
        uint4 u0 = *(const uint4*)(src + t);
        uint4 u1 = *(const uint4*)(src + t + 8);
        float2 v0 = *(const float2*)(bl + (size_t)(u0.x & 0xFFFFu) * C_);
        float2 v1 = *(const float2*)(bl + (size_t)(u0.x >> 16) * C_);
        float2 v2 = *(const float2*)(bl + (size_t)(u0.y & 0xFFFFu) * C_);
        float2 v3 = *(const float2*)(bl + (size_t)(u0.y >> 16) * C_);
        float2 v4 = *(const float2*)(bl + (size_t)(u0.z & 0xFFFFu) * C_);
        float2 v5 = *(const float2*)(bl + (size_t)(u0.z >> 16) * C_);
        float2 v6 = *(const float2*)(bl + (size_t)(u0.w & 0xFFFFu) * C_);
        float2 v7 = *(const float2*)(bl + (size_t)(u0.w >> 16) * C_);
        float2 w0 = *(const float2*)(bl + (size_t)(u1.x & 0xFFFFu) * C_);
        float2 w1 = *(const float2*)(bl + (size_t)(u1.x >> 16) * C_);
        float2 w2 = *(const float2*)(bl + (size_t)(u1.y & 0xFFFFu) * C_);
        float2 w3 = *(const float2*)(bl + (size_t)(u1.y >> 16) * C_);
        float2 w4 = *(const float2*)(bl + (size_t)(u1.z & 0xFFFFu) * C_);
        float2 w5 = *(const float2*)(bl + (size_t)(u1.z >> 16) * C_);
        float2 w6 = *(const float2*)(bl + (size_t)(u1.w & 0xFFFFu) * C_);
        float2 w7 = *(const float2*)(bl + (size_t)(u1.w >> 16) * C_);
        a0.x += v0.x + v4.x + w0.x + w4.x; a0.y += v0.y + v4.y + w0.y + w4.y;
        a1.x += v1.x + v5.x + w1.x + w5.x; a1.y += v1.y + v5.y + w1.y + w5.y;
        a2.x += v2.x + v6.x + w2.x + w6.x; a2.y += v2.y + v6.y + w2.y + w6.y;
        a3.x += v3.x + v7.x + w3.x + w7.x; a3.y += v3.y + v7.y + w3.y + w7.y;
    }
    for (; t + 8 <= cnt; t += 8) {
        uint4 u = *(const uint4*)(src + t);
        float2 v0 = *(const float2*)(bl + (size_t)(u.x & 0xFFFFu) * C_);
        float2 v1 = *(const float2*)(bl + (size_t)(u.x >> 16) * C_);
        float2 v2 = *(const float2*)(bl + (size_t)(u.y & 0xFFFFu) * C_);
        float2 v3 = *(const float2*)(bl + (size_t)(u.y >> 16) * C_);
        float2 v4 = *(const float2*)(bl + (size_t)(u.z & 0xFFFFu) * C_);
        float2 v5 = *(const float2*)(bl + (size_t)(u.z >> 16) * C_);
        float2 v6 = *(const float2*)(bl + (size_t)(u.w & 0xFFFFu) * C_);
        float2 v7 = *(const float2*)(bl + (size_t)(u.w >> 16) * C_);
        a0.x += v0.x + v4.x; a0.y += v0.y + v4.y;
        a1.x += v1.x + v5.x; a1.y += v1.y + v5.y;
        a2.x += v2.x + v6.x; a2.y += v2.y + v6.y;
        a3.x += v3.x + v7.x; a3.y += v3.y + v7.y;
    }
    for (; t < cnt; ++t) {
        float2 v = *(const float2*)(bl + (size_t)src[t] * C_);
        a0.x += v.x; a0.y += v.y;
    }
    a0.x += a1.x + a2.x + a3.x;
    a0.y += a1.y + a2.y + a3.y;
    return a0;
}

__device__ __forceinline__ void edge_src(const unsigned short* __restrict__ edgeMem,
                                         const int* __restrict__ Dv,
                                         const int* __restrict__ locCnt,
                                         const unsigned short* __restrict__ locList,
                                         int b, int e,
                                         const unsigned short*& src, int& cnt) {
    if (e < N_) {
        int rn = b * N_ + e;
        cnt = Dv[rn];
        if (cnt > CAP2_) cnt = CAP2_;
        src = edgeMem + (size_t)rn * CAP2_;
    } else {
        cnt = locCnt[e - N_];
        src = locList + (e - N_) * 32;
    }
}

// ---------------- E init: E0 = W_ev @ X (wave/edge-row, batch-per-XCD) ---------
__global__ void k_einit(const float* __restrict__ Xsrc, float* __restrict__ Edst,
                        const unsigned short* __restrict__ edgeMem, const int* __restrict__ Dv,
                        const int* __restrict__ locCnt, const unsigned short* __restrict__ locList,
                        const float* __restrict__ recipDE) {
    int b = blockIdx.x & 7;
    int e = (blockIdx.x >> 3) * 2 + (threadIdx.x >> 6);
    int lane = threadIdx.x & 63;
    if (e >= ET_) return;
    int w = b * ET_ + e;
    const unsigned short* src; int cnt;
    edge_src(edgeMem, Dv, locCnt, locList, b, e, src, cnt);
    float2 acc = gather16(Xsrc + (size_t)b * N_ * C_, src, cnt, lane);
    float r = recipDE[w];
    *(float2*)(Edst + (size_t)w * C_ + 2 * lane) = make_float2(r * acc.x, r * acc.y);
}

// ---------------- fused diffusion step: wave per row, batch-per-XCD swizzle ----
// blockIdx&7 = batch -> XCD-local X[b]+E[b]+lists working set (~2.5MB < 4MB L2).
__global__ void k_step(const float* __restrict__ Xsrc, const float* __restrict__ Esrc,
                       float* __restrict__ Xdst, float* __restrict__ Edst,
                       const unsigned short* __restrict__ edgeMem, const int* __restrict__ Dv,
                       const int* __restrict__ locCnt, const unsigned short* __restrict__ locList,
                       const int* __restrict__ nodeCnt, const unsigned short* __restrict__ nodeList,
                       const float* __restrict__ recipDV, const float* __restrict__ recipDE) {
    int b = blockIdx.x & 7;
    int local = (blockIdx.x >> 3) * 2 + (threadIdx.x >> 6);  // 0..RT_-1
    int lane = threadIdx.x & 63;
    if (local < N_) {
        int rn = b * N_ + local;
        float2 acc = gather16(Esrc + (size_t)b * ET_ * C_, nodeList + (size_t)rn * CAP_,
                              nodeCnt[rn], lane);
        size_t o = (size_t)rn * C_ + 2 * lane;
        float2 xv = *(const float2*)(Xsrc + o);
        float s = 0.05f * recipDV[rn];
        *(float2*)(Xdst + o) = make_float2(0.95f * xv.x + s * acc.x, 0.95f * xv.y + s * acc.y);
    } else {
        int e = local - N_;
        int be = b * ET_ + e;
        const unsigned short* src; int cnt;
        edge_src(edgeMem, Dv, locCnt, locList, b, e, src, cnt);
        float2 acc = gather16(Xsrc + (size_t)b * N_ * C_, src, cnt, lane);
        size_t o = (size_t)be * C_ + 2 * lane;
        float2 ev = *(const float2*)(Esrc + o);
        float s = 0.9f * recipDE[be];
        *(float2*)(Edst + o) = make_float2(0.1f * ev.x + s * acc.x, 0.1f * ev.y + s * acc.y);
    }
}

// ---------------- Z = Z + relu(Z @ W^T + bias), X and E fused ----------------
__global__ void k_transform(float* __restrict__ Xz, float* __restrict__ Ez,
                            const float* __restrict__ tvw, const float* __restrict__ tvb,
                            const float* __restrict__ tew, const float* __restrict__ teb) {
    int r = blockIdx.x;
    float* Z;
    const float *W, *bias;
    if (r < B_ * N_) { Z = Xz + (size_t)r * C_; W = tvw; bias = tvb; }
    else { Z = Ez + (size_t)(r - B_ * N_) * C_; W = tew; bias = teb; }
    int c = threadIdx.x;
    __shared__ __align__(16) float z[C_];
    z[c] = Z[c];
    __syncthreads();
    float acc = bias[c];
    const float4* w4 = (const float4*)(W + (size_t)c * C_);
    const float4* z4 = (const float4*)z;
    #pragma unroll
    for (int k = 0; k < 32; ++k) {
        float4 w = w4[k], zz = z4[k];
        acc += w.x * zz.x + w.y * zz.y + w.z * zz.z + w.w * zz.w;
    }
    Z[c] = z[c] + fmaxf(acc, 0.f);
}

// ---------------- bn_nodes: per-position norm over (B, C), X and E fused -------
__global__ void k_bn(float* __restrict__ Xz, float* __restrict__ Ez) {
    int pos = blockIdx.x;
    float* Z;
    int P;
    if (pos < N_) { Z = Xz; P = N_; }
    else { Z = Ez; P = ET_; pos -= N_; }
    int t = threadIdx.x; // 256
    __shared__ float red[256];
    float v[4];
    #pragma unroll
    for (int q = 0; q < 4; ++q) {
        int f = t + q * 256;
        int b = f >> 7, c = f & 127;
        v[q] = Z[((size_t)(b * P + pos)) * C_ + c];
    }
    float s = v[0] + v[1] + v[2] + v[3];
    red[t] = s;
    __syncthreads();
    for (int off = 128; off > 0; off >>= 1) {
        if (t < off) red[t] += red[t + off];
        __syncthreads();
    }
    float m = red[0] * (1.0f / 1024.0f);
    __syncthreads();
    float s2 = 0.f;
    #pragma unroll
    for (int q = 0; q < 4; ++q) { float d = v[q] - m; s2 += d * d; }
    red[t] = s2;
    __syncthreads();
    for (int off = 128; off > 0; off >>= 1) {
        if (t < off) red[t] += red[t + off];
        __syncthreads();
    }
    float rstd = rsqrtf(red[0] * (1.0f / 1024.0f) + 1e-5f);
    #pragma unroll
    for (int q = 0; q < 4; ++q) {
        int f = t + q * 256;
        int b = f >> 7, c = f & 127;
        Z[((size_t)(b * P + pos)) * C_ + c] = (v[q] - m) * rstd;
    }
}

// ---------------- final per-channel stats over (B,N) ----------------
__global__ void k_finstats(const float* __restrict__ Xf, float* __restrict__ stats) {
    int c = blockIdx.x;  // 128
    int t = threadIdx.x; // 256
    __shared__ float rs[256], rs2[256];
    float s = 0.f, s2 = 0.f;
    for (int r = t; r < B_ * N_; r += 256) {
        float x = Xf[(size_t)r * C_ + c];
        s += x;
        s2 += x * x;
    }
    rs[t] = s; rs2[t] = s2;
    __syncthreads();
    for (int off = 128; off > 0; off >>= 1) {
        if (t < off) { rs[t] += rs[t + off]; rs2[t] += rs2[t + off]; }
        __syncthreads();
    }
    if (t == 0) {
        float m = rs[0] / (float)(B_ * N_);
        float var = rs2[0] / (float)(B_ * N_) - m * m;
        stats[c] = m;
        stats[C_ + c] = rsqrtf(var + 1e-5f);
    }
}

__global__ void k_finapply(const float* __restrict__ Xf, const float* __restrict__ Xin,
                           const float* __restrict__ stats, const float* __restrict__ bnw,
                           const float* __restrict__ bnb, float* __restrict__ out) {
    size_t i = (size_t)blockIdx.x * blockDim.x + threadIdx.x;
    if (i >= (size_t)B_ * N_ * C_) return;
    int c = (int)(i & (C_ - 1));
    float x = Xf[i];
    float xn = (x - stats[c]) * stats[C_ + c] * bnw[c] + bnb[c];
    out[i] = fmaxf(xn, 0.f) + Xin[i];
}

extern "C" void kernel_launch(void* const* d_in, const int* in_sizes, int n_in,
                              void* d_out, int out_size, void* d_ws, size_t ws_size,
                              hipStream_t stream) {
    const float* Xin = (const float*)d_in[0];
    const float* localH = (const float*)d_in[1];
    const float* tv_w = (const float*)d_in[2];
    const float* tv_b = (const float*)d_in[3];
    const float* te_w = (const float*)d_in[4];
    const float* te_b = (const float*)d_in[5];
    const float* bn_w = (const float*)d_in[6];
    const float* bn_b = (const float*)d_in[7];
    float* out = (float*)d_out;

    char* base = (char*)d_ws;
    size_t off = 0;
    auto alloc = [&](size_t bytes) -> void* {
        void* p = base + off;
        off = (off + bytes + 255) & ~(size_t)255;
        return p;
    };
    float* D = (float*)alloc((size_t)B_ * N_ * N_ * 4);
    float* x2 = (float*)alloc((size_t)B_ * N_ * 4);
    int* Dv = (int*)alloc((size_t)B_ * N_ * 4);
    int* nodeCnt = (int*)alloc((size_t)B_ * N_ * 4);
    unsigned short* nodeList = (unsigned short*)alloc((size_t)B_ * N_ * CAP_ * 2);
    float* recipDV = (float*)alloc((size_t)B_ * N_ * 4);
    float* recipDE = (float*)alloc((size_t)B_ * ET_ * 4);
    int* locCnt = (int*)alloc(256 * 4);
    unsigned short* locList = (unsigned short*)alloc((size_t)EL_ * 32 * 2);
    unsigned short* edgeMem = (unsigned short*)alloc((size_t)B_ * N_ * CAP2_ * 2);
    float* X0 = (float*)alloc((size_t)B_ * N_ * C_ * 4);
    float* X1 = (float*)alloc((size_t)B_ * N_ * C_ * 4);
    float* E0 = (float*)alloc((size_t)B_ * ET_ * C_ * 4);
    float* E1 = (float*)alloc((size_t)B_ * ET_ * C_ * 4);
    float* stats = (float*)alloc(2 * C_ * 4);
    if (off > ws_size) return;

    hipMemsetAsync(Dv, 0, (size_t)B_ * N_ * 4, stream);
    hipMemsetAsync(nodeCnt, 0, (size_t)B_ * N_ * 4, stream);
    hipMemcpyAsync(X0, Xin, (size_t)B_ * N_ * C_ * 4, hipMemcpyDeviceToDevice, stream);

    k_x2<<<B_ * N_ / 4, 256, 0, stream>>>(Xin, x2);
    k_dist<<<B_ * 64, 256, 0, stream>>>(Xin, x2, D);
    k_top11dv<<<B_ * N_ / 4, 256, 0, stream>>>(D, Dv);
    k_locbuild<<<(EL_ * 64 + 255) / 256, 256, 0, stream>>>(localH, locCnt, locList);
    k_edgebuild<<<(B_ * ET_ + 3) / 4, 256, 0, stream>>>(D, Dv, locCnt, locList, edgeMem,
                                                        nodeCnt, nodeList, recipDE);
    k_sortlists<<<B_ * N_ / 4, 256, 0, stream>>>(nodeCnt, nodeList, recipDV);
    k_einit<<<B_ * (ET_ / 2 + 1), 128, 0, stream>>>(X0, E0, edgeMem, Dv, locCnt, locList,
                                                    recipDE);

    float* Xc = X0; float* Xn = X1; float* Ec = E0; float* En = E1;
    const int ROWS = B_ * N_ + B_ * ET_;
    for (int i = 0; i < 40; ++i) {
        if (i % 20 == 0) {
            k_transform<<<ROWS, 128, 0, stream>>>(Xc, Ec, tv_w, tv_b, te_w, te_b);
            k_bn<<<N_ + ET_, 256, 0, stream>>>(Xc, Ec);
        }
        k_step<<<B_ * (RT_ / 2), 128, 0, stream>>>(Xc, Ec, Xn, En, edgeMem, Dv, locCnt,
                                                   locList, nodeCnt, nodeList, recipDV,
                                                   recipDE);
        float* t;
        t = Xc; Xc = Xn; Xn = t;
        t = Ec; Ec = En; En = t;
    }

    k_finstats<<<C_, 256, 0, stream>>>(Xc, stats);
    k_finapply<<<(B_ * N_ * C_ + 255) / 256, 256, 0, stream>>>(Xc, Xin, stats, bn_w, bn_b, out);
}

// Round 9
// 971.807 us; speedup vs baseline: 6.7821x; 1.2074x over previous
//
#include <hip/hip_runtime.h>
#include <hip/hip_bf16.h>

constexpr int B_ = 8;
constexpr int N_ = 1024;      // nodes
constexpr int C_ = 128;       // channels
constexpr int EL_ = 196;      // local edges
constexpr int ET_ = N_ + EL_; // 1220 total edges
constexpr int RT_ = N_ + ET_; // 2244 rows (node+edge) per batch
constexpr int KNN_ = 11;      // k+1
constexpr int CAP_ = 512;     // per-node edge-list capacity (u16 entries)
constexpr int CAP2_ = 512;    // per-edge member capacity

// ---------------- x2 = sum(x*x) per row ----------------
__global__ void k_x2(const float* __restrict__ X, float* __restrict__ x2) {
    int row = blockIdx.x * 4 + (threadIdx.x >> 6);
    int lane = threadIdx.x & 63;
    const float* xr = X + (size_t)row * C_;
    float a = xr[lane], b = xr[lane + 64];
    float s = a * a + b * b;
    #pragma unroll
    for (int off = 32; off > 0; off >>= 1) s += __shfl_down(s, off, 64);
    if (lane == 0) x2[row] = s;
}

// ---------------- distance matrix: tiled 128x128 GEMM, batch-per-XCD ----------
__global__ __launch_bounds__(256) void k_dist(const float* __restrict__ X,
                                              const float* __restrict__ x2,
                                              float* __restrict__ D) {
    __shared__ float As[32][132];
    __shared__ float Bs[32][132];
    int b = blockIdx.x & 7;
    int t = blockIdx.x >> 3;
    int ti = t >> 3, tj = t & 7;
    const float* Xb = X + (size_t)b * N_ * C_;
    int tid = threadIdx.x;
    int tx = tid & 15, ty = tid >> 4;
    float acc[8][8];
    #pragma unroll
    for (int i = 0; i < 8; ++i)
        #pragma unroll
        for (int j = 0; j < 8; ++j) acc[i][j] = 0.f;
    for (int kc = 0; kc < 4; ++kc) {
        __syncthreads();
        #pragma unroll
        for (int q = 0; q < 4; ++q) {
            int id = tid + q * 256;
            int r = id >> 3, kk = (id & 7) * 4;
            float4 av = *(const float4*)(Xb + (size_t)(ti * 128 + r) * C_ + kc * 32 + kk);
            As[kk + 0][r] = av.x; As[kk + 1][r] = av.y;
            As[kk + 2][r] = av.z; As[kk + 3][r] = av.w;
            float4 bv = *(const float4*)(Xb + (size_t)(tj * 128 + r) * C_ + kc * 32 + kk);
            Bs[kk + 0][r] = bv.x; Bs[kk + 1][r] = bv.y;
            Bs[kk + 2][r] = bv.z; Bs[kk + 3][r] = bv.w;
        }
        __syncthreads();
        #pragma unroll 8
        for (int k = 0; k < 32; ++k) {
            float a[8], bb[8];
            *(float4*)(a + 0) = *(const float4*)&As[k][ty * 8];
            *(float4*)(a + 4) = *(const float4*)&As[k][ty * 8 + 4];
            *(float4*)(bb + 0) = *(const float4*)&Bs[k][tx * 8];
            *(float4*)(bb + 4) = *(const float4*)&Bs[k][tx * 8 + 4];
            #pragma unroll
            for (int i = 0; i < 8; ++i)
                #pragma unroll
                for (int j = 0; j < 8; ++j) acc[i][j] += a[i] * bb[j];
        }
    }
    float x2r[8], x2c[8];
    #pragma unroll
    for (int i = 0; i < 8; ++i) x2r[i] = x2[b * N_ + ti * 128 + ty * 8 + i];
    #pragma unroll
    for (int j = 0; j < 8; ++j) x2c[j] = x2[b * N_ + tj * 128 + tx * 8 + j];
    #pragma unroll
    for (int i = 0; i < 8; ++i) {
        int m = ti * 128 + ty * 8 + i;
        float* drow = D + ((size_t)(b * N_ + m)) * N_ + tj * 128 + tx * 8;
        float4 o0, o1;
        o0.x = x2r[i] - 2.f * acc[i][0] + x2c[0];
        o0.y = x2r[i] - 2.f * acc[i][1] + x2c[1];
        o0.z = x2r[i] - 2.f * acc[i][2] + x2c[2];
        o0.w = x2r[i] - 2.f * acc[i][3] + x2c[3];
        o1.x = x2r[i] - 2.f * acc[i][4] + x2c[4];
        o1.y = x2r[i] - 2.f * acc[i][5] + x2c[5];
        o1.z = x2r[i] - 2.f * acc[i][6] + x2c[6];
        o1.w = x2r[i] - 2.f * acc[i][7] + x2c[7];
        *(float4*)drow = o0;
        *(float4*)(drow + 4) = o1;
    }
}

// monotone map: float total order -> u32 unsigned order
__device__ __forceinline__ unsigned mapdist(float d) {
    unsigned u = __float_as_uint(d);
    return u ^ (unsigned)(((int)u >> 31) | 0x80000000);
}

// wave-parallel top-m selection thresholds; replicates stable argsort exactly
struct SelThresh { unsigned theta; unsigned psi; };

__device__ __forceinline__ SelThresh wave_topm(const unsigned (&md)[16],
                                               const int (&col)[16], int m) {
    unsigned pfx = 0;
    for (int b = 31; b >= 0; --b) {
        unsigned cand = pfx | (1u << b);
        int c = 0;
        #pragma unroll
        for (int i = 0; i < 16; ++i)
            c += __popcll(__ballot(md[i] < cand));
        if (c < m) pfx = cand;
    }
    unsigned theta = pfx;
    int cLt = 0;
    #pragma unroll
    for (int i = 0; i < 16; ++i)
        cLt += __popcll(__ballot(md[i] < theta));
    int t = m - cLt;  // >= 1
    unsigned ppfx = 0;
    for (int b = 9; b >= 0; --b) {
        unsigned cand = ppfx | (1u << b);
        int c = 0;
        #pragma unroll
        for (int i = 0; i < 16; ++i)
            c += __popcll(__ballot(md[i] == theta && (unsigned)col[i] < cand));
        if (c < t) ppfx = cand;
    }
    return {theta, ppfx};
}

__device__ __forceinline__ void load_row16(const float* __restrict__ Drow, int lane,
                                           unsigned (&md)[16], int (&col)[16]) {
    const float4* row4 = (const float4*)Drow;
    #pragma unroll
    for (int j = 0; j < 4; ++j) {
        float4 v = row4[j * 64 + lane];
        int c0 = (j * 64 + lane) * 4;
        md[j * 4 + 0] = mapdist(v.x); col[j * 4 + 0] = c0 + 0;
        md[j * 4 + 1] = mapdist(v.y); col[j * 4 + 1] = c0 + 1;
        md[j * 4 + 2] = mapdist(v.z); col[j * 4 + 2] = c0 + 2;
        md[j * 4 + 3] = mapdist(v.w); col[j * 4 + 3] = c0 + 3;
    }
}

// ---------------- top-11 per row -> Dv atomics (wave per row, radix select) ----
__global__ __launch_bounds__(256) void k_top11dv(const float* __restrict__ D,
                                                 int* __restrict__ Dv) {
    int w = (blockIdx.x * 256 + threadIdx.x) >> 6;
    int lane = threadIdx.x & 63;
    if (w >= B_ * N_) return;
    int b = w >> 10;
    unsigned md[16]; int col[16];
    load_row16(D + (size_t)w * N_, lane, md, col);
    SelThresh st = wave_topm(md, col, KNN_);
    #pragma unroll
    for (int i = 0; i < 16; ++i) {
        bool in = (md[i] < st.theta) || (md[i] == st.theta && (unsigned)col[i] <= st.psi);
        if (in) atomicAdd(&Dv[b * N_ + col[i]], 1);
    }
}

// ---------------- local edge member lists: wave per edge, ordered compaction ----
__global__ void k_locbuild(const float* __restrict__ localH, int* __restrict__ locCnt,
                           unsigned short* __restrict__ locList) {
    int w = (blockIdx.x * blockDim.x + threadIdx.x) >> 6;
    int lane = threadIdx.x & 63;
    if (w >= EL_) return;
    int le = w;
    int base = 0;
    for (int chunk = 0; chunk < N_ / 64; ++chunk) {
        int n = chunk * 64 + lane;
        bool m = localH[(size_t)n * EL_ + le] != 0.0f;
        unsigned long long mask = __ballot(m);
        if (m) {
            int pos = base + __popcll(mask & ((1ull << lane) - 1ull));
            locList[le * 32 + pos] = (unsigned short)n;
        }
        base += __popcll(mask);
    }
    if (lane == 0) locCnt[le] = base;
}

// ------- edge member selection (radix) + ballot-compact + parallel scatter -----
__global__ __launch_bounds__(256) void k_edgebuild(const float* __restrict__ D,
                                                   const int* __restrict__ Dv,
                                                   const int* __restrict__ locCnt,
                                                   const unsigned short* __restrict__ locList,
                                                   unsigned short* __restrict__ edgeMem,
                                                   int* __restrict__ nodeCnt,
                                                   unsigned short* __restrict__ nodeList,
                                                   float* __restrict__ recipDE) {
    int w = (blockIdx.x * 256 + threadIdx.x) >> 6;
    int lane = threadIdx.x & 63;
    if (w >= B_ * ET_) return;
    int b = w / ET_, e = w - b * ET_;
    if (e < N_) {
        int rn = b * N_ + e;
        int full = Dv[rn];
        int m = full < CAP2_ ? full : CAP2_;
        unsigned md[16]; int col[16];
        load_row16(D + (size_t)rn * N_, lane, md, col);
        SelThresh st = wave_topm(md, col, m);
        int base = 0;
        #pragma unroll
        for (int i = 0; i < 16; ++i) {
            bool in = (md[i] < st.theta) || (md[i] == st.theta && (unsigned)col[i] <= st.psi);
            unsigned long long bal = __ballot(in);
            if (in) {
                int pos = base + __popcll(bal & ((1ull << lane) - 1ull));
                edgeMem[(size_t)rn * CAP2_ + pos] = (unsigned short)col[i];
                int p2 = atomicAdd(&nodeCnt[b * N_ + col[i]], 1);
                if (p2 < CAP_) nodeList[((size_t)(b * N_ + col[i])) * CAP_ + p2] = (unsigned short)e;
            }
            base += __popcll(bal);
        }
        if (lane == 0) recipDE[w] = 1.0f / (float)full;
    } else {
        int le = e - N_;
        int cnt = locCnt[le];
        for (int t = lane; t < cnt; t += 64) {
            int j = locList[le * 32 + t];
            int pos = atomicAdd(&nodeCnt[b * N_ + j], 1);
            if (pos < CAP_) nodeList[((size_t)(b * N_ + j)) * CAP_ + pos] = (unsigned short)e;
        }
        if (lane == 0) recipDE[w] = 1.0f / (float)cnt;
    }
}

// ---------------- wave-per-node rank sort (edge ids unique) + recipDV ----------
__global__ __launch_bounds__(256) void k_sortlists(int* __restrict__ nodeCnt,
                                                   unsigned short* __restrict__ nodeList,
                                                   float* __restrict__ recipDV) {
    __shared__ int sl[4][CAP_];
    int w = threadIdx.x >> 6;
    int lane = threadIdx.x & 63;
    int rn = blockIdx.x * 4 + w;
    int cnt = nodeCnt[rn];
    if (cnt > CAP_) cnt = CAP_;
    unsigned short* g = nodeList + (size_t)rn * CAP_;
    for (int t = lane; t < cnt; t += 64) sl[w][t] = g[t];
    __syncthreads();
    for (int t = lane; t < cnt; t += 64) {
        int v = sl[w][t];
        int rank = 0;
        for (int j = 0; j < cnt; ++j) rank += (sl[w][j] < v) ? 1 : 0;
        g[rank] = (unsigned short)v;
    }
    if (lane == 0) {
        recipDV[rn] = 1.0f / (float)cnt;
        nodeCnt[rn] = cnt;
    }
}

// ---------------- 16-way ILP gather: u16 indices, 8 per uint4 load -------------
__device__ __forceinline__ float2 gather16(const float* __restrict__ base,
                                           const unsigned short* __restrict__ src,
                                           int cnt, int lane) {
    float2 a0 = {0.f, 0.f}, a1 = {0.f, 0.f}, a2 = {0.f, 0.f}, a3 = {0.f, 0.f};
    const float* bl = base + 2 * lane;
    int t = 0;
    for (; t + 16 <= cnt; t += 16) {
        uint4 u0 = *(const uint4*)(src + t);
        uint4 u1 = *(const uint4*)(src + t + 8);
        float2 v0 = *(const float2*)(bl + (size_t)(u0.x & 0xFFFFu) * C_);
        float2 v1 = *(const float2*)(bl + (size_t)(u0.x >> 16) * C_);
        float2 v2 = *(const float2*)(bl + (size_t)(u0.y & 0xFFFFu) * C_);
        float2 v3 = *(const float2*)(bl + (size_t)(u0.y >> 16) * C_);
        float2 v4 = *(const float2*)(bl + (size_t)(u0.z & 0xFFFFu) * C_);
        float2 v5 = *(const float2*)(bl + (size_t)(u0.z >> 16) * C_);
        float2 v6 = *(const float2*)(bl + (size_t)(u0.w & 0xFFFFu) * C_);
        float2 v7 = *(const float2*)(bl + (size_t)(u0.w >> 16) * C_);
        float2 w0 = *(const float2*)(bl + (size_t)(u1.x & 0xFFFFu) * C_);
        float2 w1 = *(const float2*)(bl + (size_t)(u1.x >> 16) * C_);
        float2 w2 = *(const float2*)(bl + (size_t)(u1.y & 0xFFFFu) * C_);
        float2 w3 = *(const float2*)(bl + (size_t)(u1.y >> 16) * C_);
        float2 w4 = *(const float2*)(bl + (size_t)(u1.z & 0xFFFFu) * C_);
        float2 w5 = *(const float2*)(bl + (size_t)(u1.z >> 16) * C_);
        float2 w6 = *(const float2*)(bl + (size_t)(u1.w & 0xFFFFu) * C_);
        float2 w7 = *(const float2*)(bl + (size_t)(u1.w >> 16) * C_);
        a0.x += v0.x + v4.x + w0.x + w4.x; a0.y += v0.y + v4.y + w0.y + w4.y;
        a1.x += v1.x + v5.x + w1.x + w5.x; a1.y += v1.y + v5.y + w1.y + w5.y;
        a2.x += v2.x + v6.x + w2.x + w6.x; a2.y += v2.y + v6.y + w2.y + w6.y;
        a3.x += v3.x + v7.x + w3.x + w7.x; a3.y += v3.y + v7.y + w3.y + w7.y;
    }
    for (; t + 8 <= cnt; t += 8) {
        uint4 u = *(const uint4*)(src + t);
        float2 v0 = *(const float2*)(bl + (size_t)(u.x & 0xFFFFu) * C_);
        float2 v1 = *(const float2*)(bl + (size_t)(u.x >> 16) * C_);
        float2 v2 = *(const float2*)(bl + (size_t)(u.y & 0xFFFFu) * C_);
        float2 v3 = *(const float2*)(bl + (size_t)(u.y >> 16) * C_);
        float2 v4 = *(const float2*)(bl + (size_t)(u.z & 0xFFFFu) * C_);
        float2 v5 = *(const float2*)(bl + (size_t)(u.z >> 16) * C_);
        float2 v6 = *(const float2*)(bl + (size_t)(u.w & 0xFFFFu) * C_);
        float2 v7 = *(const float2*)(bl + (size_t)(u.w >> 16) * C_);
        a0.x += v0.x + v4.x; a0.y += v0.y + v4.y;
        a1.x += v1.x + v5.x; a1.y += v1.y + v5.y;
        a2.x += v2.x + v6.x; a2.y += v2.y + v6.y;
        a3.x += v3.x + v7.x; a3.y += v3.y + v7.y;
    }
    for (; t < cnt; ++t) {
        float2 v = *(const float2*)(bl + (size_t)src[t] * C_);
        a0.x += v.x; a0.y += v.y;
    }
    a0.x += a1.x + a2.x + a3.x;
    a0.y += a1.y + a2.y + a3.y;
    return a0;
}

__device__ __forceinline__ void edge_src(const unsigned short* __restrict__ edgeMem,
                                         const int* __restrict__ Dv,
                                         const int* __restrict__ locCnt,
                                         const unsigned short* __restrict__ locList,
                                         int b, int e,
                                         const unsigned short*& src, int& cnt) {
    if (e < N_) {
        int rn = b * N_ + e;
        cnt = Dv[rn];
        if (cnt > CAP2_) cnt = CAP2_;
        src = edgeMem + (size_t)rn * CAP2_;
    } else {
        cnt = locCnt[e - N_];
        src = locList + (e - N_) * 32;
    }
}

// ---------------- E init: E0 = W_ev @ X (wave/edge-row, batch-per-XCD) ---------
__global__ void k_einit(const float* __restrict__ Xsrc, float* __restrict__ Edst,
                        const unsigned short* __restrict__ edgeMem, const int* __restrict__ Dv,
                        const int* __restrict__ locCnt, const unsigned short* __restrict__ locList,
                        const float* __restrict__ recipDE) {
    int b = blockIdx.x & 7;
    int e = (blockIdx.x >> 3) * 2 + (threadIdx.x >> 6);
    int lane = threadIdx.x & 63;
    if (e >= ET_) return;
    int w = b * ET_ + e;
    const unsigned short* src; int cnt;
    edge_src(edgeMem, Dv, locCnt, locList, b, e, src, cnt);
    float2 acc = gather16(Xsrc + (size_t)b * N_ * C_, src, cnt, lane);
    float r = recipDE[w];
    *(float2*)(Edst + (size_t)w * C_ + 2 * lane) = make_float2(r * acc.x, r * acc.y);
}

// ---------------- fused diffusion step: wave per row, batch-per-XCD swizzle ----
__global__ void k_step(const float* __restrict__ Xsrc, const float* __restrict__ Esrc,
                       float* __restrict__ Xdst, float* __restrict__ Edst,
                       const unsigned short* __restrict__ edgeMem, const int* __restrict__ Dv,
                       const int* __restrict__ locCnt, const unsigned short* __restrict__ locList,
                       const int* __restrict__ nodeCnt, const unsigned short* __restrict__ nodeList,
                       const float* __restrict__ recipDV, const float* __restrict__ recipDE) {
    int b = blockIdx.x & 7;
    int local = (blockIdx.x >> 3) * 2 + (threadIdx.x >> 6);  // 0..RT_-1
    int lane = threadIdx.x & 63;
    if (local < N_) {
        int rn = b * N_ + local;
        float2 acc = gather16(Esrc + (size_t)b * ET_ * C_, nodeList + (size_t)rn * CAP_,
                              nodeCnt[rn], lane);
        size_t o = (size_t)rn * C_ + 2 * lane;
        float2 xv = *(const float2*)(Xsrc + o);
        float s = 0.05f * recipDV[rn];
        *(float2*)(Xdst + o) = make_float2(0.95f * xv.x + s * acc.x, 0.95f * xv.y + s * acc.y);
    } else {
        int e = local - N_;
        int be = b * ET_ + e;
        const unsigned short* src; int cnt;
        edge_src(edgeMem, Dv, locCnt, locList, b, e, src, cnt);
        float2 acc = gather16(Xsrc + (size_t)b * N_ * C_, src, cnt, lane);
        size_t o = (size_t)be * C_ + 2 * lane;
        float2 ev = *(const float2*)(Esrc + o);
        float s = 0.9f * recipDE[be];
        *(float2*)(Edst + o) = make_float2(0.1f * ev.x + s * acc.x, 0.1f * ev.y + s * acc.y);
    }
}

// ------- Z = Z + relu(Z @ W^T + bias): 16 rows/block, W amortized 16x ---------
// Blocks [0, XB): X rows; [XB, XB+EB): E rows. 128 threads; thread c owns output
// column c for all 16 rows. Z rows staged in LDS; z float4 reads are uniform
// per-thread -> LDS broadcast (conflict-free). 16 independent FMA chains.
constexpr int XB_ = B_ * N_ / 16;   // 512
constexpr int EB_ = B_ * ET_ / 16;  // 610
__global__ __launch_bounds__(128) void k_transform(float* __restrict__ Xz,
                                                   float* __restrict__ Ez,
                                                   const float* __restrict__ tvw,
                                                   const float* __restrict__ tvb,
                                                   const float* __restrict__ tew,
                                                   const float* __restrict__ teb) {
    __shared__ __align__(16) float zs[16][C_];
    int blk = blockIdx.x;
    float* Z;
    const float *W, *bias;
    if (blk < XB_) { Z = Xz + (size_t)blk * 16 * C_; W = tvw; bias = tvb; }
    else { Z = Ez + (size_t)(blk - XB_) * 16 * C_; W = tew; bias = teb; }
    int c = threadIdx.x;
    const float4* Zg4 = (const float4*)Z;
    float4* zs4 = (float4*)zs;
    #pragma unroll
    for (int q = 0; q < 4; ++q) zs4[c + q * 128] = Zg4[c + q * 128];
    __syncthreads();
    float acc[16];
    float bc = bias[c];
    #pragma unroll
    for (int r = 0; r < 16; ++r) acc[r] = bc;
    const float4* w4 = (const float4*)(W + (size_t)c * C_);
    #pragma unroll 4
    for (int k = 0; k < 32; ++k) {
        float4 w = w4[k];
        #pragma unroll
        for (int r = 0; r < 16; ++r) {
            float4 z = ((const float4*)zs[r])[k];
            acc[r] += w.x * z.x + w.y * z.y + w.z * z.z + w.w * z.w;
        }
    }
    #pragma unroll
    for (int r = 0; r < 16; ++r)
        Z[(size_t)r * C_ + c] = zs[r][c] + fmaxf(acc[r], 0.f);
}

// ---------------- bn_nodes: per-position norm over (B, C), X and E fused -------
__global__ void k_bn(float* __restrict__ Xz, float* __restrict__ Ez) {
    int pos = blockIdx.x;
    float* Z;
    int P;
    if (pos < N_) { Z = Xz; P = N_; }
    else { Z = Ez; P = ET_; pos -= N_; }
    int t = threadIdx.x; // 256
    __shared__ float red[256];
    float v[4];
    #pragma unroll
    for (int q = 0; q < 4; ++q) {
        int f = t + q * 256;
        int b = f >> 7, c = f & 127;
        v[q] = Z[((size_t)(b * P + pos)) * C_ + c];
    }
    float s = v[0] + v[1] + v[2] + v[3];
    red[t] = s;
    __syncthreads();
    for (int off = 128; off > 0; off >>= 1) {
        if (t < off) red[t] += red[t + off];
        __syncthreads();
    }
    float m = red[0] * (1.0f / 1024.0f);
    __syncthreads();
    float s2 = 0.f;
    #pragma unroll
    for (int q = 0; q < 4; ++q) { float d = v[q] - m; s2 += d * d; }
    red[t] = s2;
    __syncthreads();
    for (int off = 128; off > 0; off >>= 1) {
        if (t < off) red[t] += red[t + off];
        __syncthreads();
    }
    float rstd = rsqrtf(red[0] * (1.0f / 1024.0f) + 1e-5f);
    #pragma unroll
    for (int q = 0; q < 4; ++q) {
        int f = t + q * 256;
        int b = f >> 7, c = f & 127;
        Z[((size_t)(b * P + pos)) * C_ + c] = (v[q] - m) * rstd;
    }
}

// ---------------- final per-channel stats over (B,N) ----------------
__global__ void k_finstats(const float* __restrict__ Xf, float* __restrict__ stats) {
    int c = blockIdx.x;  // 128
    int t = threadIdx.x; // 256
    __shared__ float rs[256], rs2[256];
    float s = 0.f, s2 = 0.f;
    for (int r = t; r < B_ * N_; r += 256) {
        float x = Xf[(size_t)r * C_ + c];
        s += x;
        s2 += x * x;
    }
    rs[t] = s; rs2[t] = s2;
    __syncthreads();
    for (int off = 128; off > 0; off >>= 1) {
        if (t < off) { rs[t] += rs[t + off]; rs2[t] += rs2[t + off]; }
        __syncthreads();
    }
    if (t == 0) {
        float m = rs[0] / (float)(B_ * N_);
        float var = rs2[0] / (float)(B_ * N_) - m * m;
        stats[c] = m;
        stats[C_ + c] = rsqrtf(var + 1e-5f);
    }
}

__global__ void k_finapply(const float* __restrict__ Xf, const float* __restrict__ Xin,
                           const float* __restrict__ stats, const float* __restrict__ bnw,
                           const float* __restrict__ bnb, float* __restrict__ out) {
    size_t i = (size_t)blockIdx.x * blockDim.x + threadIdx.x;
    if (i >= (size_t)B_ * N_ * C_) return;
    int c = (int)(i & (C_ - 1));
    float x = Xf[i];
    float xn = (x - stats[c]) * stats[C_ + c] * bnw[c] + bnb[c];
    out[i] = fmaxf(xn, 0.f) + Xin[i];
}

extern "C" void kernel_launch(void* const* d_in, const int* in_sizes, int n_in,
                              void* d_out, int out_size, void* d_ws, size_t ws_size,
                              hipStream_t stream) {
    const float* Xin = (const float*)d_in[0];
    const float* localH = (const float*)d_in[1];
    const float* tv_w = (const float*)d_in[2];
    const float* tv_b = (const float*)d_in[3];
    const float* te_w = (const float*)d_in[4];
    const float* te_b = (const float*)d_in[5];
    const float* bn_w = (const float*)d_in[6];
    const float* bn_b = (const float*)d_in[7];
    float* out = (float*)d_out;

    char* base = (char*)d_ws;
    size_t off = 0;
    auto alloc = [&](size_t bytes) -> void* {
        void* p = base + off;
        off = (off + bytes + 255) & ~(size_t)255;
        return p;
    };
    float* D = (float*)alloc((size_t)B_ * N_ * N_ * 4);
    float* x2 = (float*)alloc((size_t)B_ * N_ * 4);
    int* Dv = (int*)alloc((size_t)B_ * N_ * 4);
    int* nodeCnt = (int*)alloc((size_t)B_ * N_ * 4);
    unsigned short* nodeList = (unsigned short*)alloc((size_t)B_ * N_ * CAP_ * 2);
    float* recipDV = (float*)alloc((size_t)B_ * N_ * 4);
    float* recipDE = (float*)alloc((size_t)B_ * ET_ * 4);
    int* locCnt = (int*)alloc(256 * 4);
    unsigned short* locList = (unsigned short*)alloc((size_t)EL_ * 32 * 2);
    unsigned short* edgeMem = (unsigned short*)alloc((size_t)B_ * N_ * CAP2_ * 2);
    float* X0 = (float*)alloc((size_t)B_ * N_ * C_ * 4);
    float* X1 = (float*)alloc((size_t)B_ * N_ * C_ * 4);
    float* E0 = (float*)alloc((size_t)B_ * ET_ * C_ * 4);
    float* E1 = (float*)alloc((size_t)B_ * ET_ * C_ * 4);
    float* stats = (float*)alloc(2 * C_ * 4);
    if (off > ws_size) return;

    hipMemsetAsync(Dv, 0, (size_t)B_ * N_ * 4, stream);
    hipMemsetAsync(nodeCnt, 0, (size_t)B_ * N_ * 4, stream);
    hipMemcpyAsync(X0, Xin, (size_t)B_ * N_ * C_ * 4, hipMemcpyDeviceToDevice, stream);

    k_x2<<<B_ * N_ / 4, 256, 0, stream>>>(Xin, x2);
    k_dist<<<B_ * 64, 256, 0, stream>>>(Xin, x2, D);
    k_top11dv<<<B_ * N_ / 4, 256, 0, stream>>>(D, Dv);
    k_locbuild<<<(EL_ * 64 + 255) / 256, 256, 0, stream>>>(localH, locCnt, locList);
    k_edgebuild<<<(B_ * ET_ + 3) / 4, 256, 0, stream>>>(D, Dv, locCnt, locList, edgeMem,
                                                        nodeCnt, nodeList, recipDE);
    k_sortlists<<<B_ * N_ / 4, 256, 0, stream>>>(nodeCnt, nodeList, recipDV);
    k_einit<<<B_ * (ET_ / 2 + 1), 128, 0, stream>>>(X0, E0, edgeMem, Dv, locCnt, locList,
                                                    recipDE);

    float* Xc = X0; float* Xn = X1; float* Ec = E0; float* En = E1;
    for (int i = 0; i < 40; ++i) {
        if (i % 20 == 0) {
            k_transform<<<XB_ + EB_, 128, 0, stream>>>(Xc, Ec, tv_w, tv_b, te_w, te_b);
            k_bn<<<N_ + ET_, 256, 0, stream>>>(Xc, Ec);
        }
        k_step<<<B_ * (RT_ / 2), 128, 0, stream>>>(Xc, Ec, Xn, En, edgeMem, Dv, locCnt,
                                                   locList, nodeCnt, nodeList, recipDV,
                                                   recipDE);
        float* t;
        t = Xc; Xc = Xn; Xn = t;
        t = Ec; Ec = En; En = t;
    }

    k_finstats<<<C_, 256, 0, stream>>>(Xc, stats);
    k_finapply<<<(B_ * N_ * C_ + 255) / 256, 256, 0, stream>>>(Xc, Xin, stats, bn_w, bn_b, out);
}